// Round 5
// baseline (1465.580 us; speedup 1.0000x reference)
//
#include <hip/hip_runtime.h>
#include <hip/hip_fp16.h>
#include <math.h>

#define TDIM 100      // D
#define EDGED 101     // D + MSG_DIM (logical)
#define EDGEP 104     // padded qW row stride (halfs), even -> half2-aligned
#define HALFC 50      // per-head channels
#define WET_PAD 10240 // padded float count for WeT region
#define NCOLP 640     // padded fused-output columns (602 real)
#define KPAD 128      // padded K (100 real)
#define SCB 256

typedef __attribute__((ext_vector_type(8))) _Float16 f16x8;
typedef __attribute__((ext_vector_type(4))) float f32x4;

// ---------------- K0: assoc + WeT transpose + deg zero ----------------
__global__ void k_prep(const int* __restrict__ n_id, int N,
                       const float* __restrict__ We,
                       int* __restrict__ assoc, int* __restrict__ deg,
                       float* __restrict__ WeT) {
    int i = blockIdx.x * blockDim.x + threadIdx.x;
    if (i < N) {
        assoc[n_id[i]] = i;
        deg[i] = 0;
    }
    if (i < WET_PAD) {
        if (i < EDGED * TDIM) {
            int j = i / TDIM, d = i - j * TDIM;   // WeT[j][d] = We[d][j]
            WeT[i] = We[d * EDGED + j];
        } else {
            WeT[i] = 0.f;
        }
    }
}

// ---------------- K0a: fused transposed weight WT[col][k] (fp16 hi/lo) --------
__global__ __launch_bounds__(256) void k_precomp2(
    const float* __restrict__ Wq, const float* __restrict__ bq,
    const float* __restrict__ Wk, const float* __restrict__ bk,
    const float* __restrict__ Wv, const float* __restrict__ bv,
    const float* __restrict__ Ws, const float* __restrict__ bs,
    const float* __restrict__ We,
    __half* __restrict__ WTh, __half* __restrict__ WTl,
    float* __restrict__ bias_all)
{
    int t = blockIdx.x * blockDim.x + threadIdx.x;
    if (t < NCOLP * KPAD) {
        int col = t >> 7, k = t & 127;
        float val = 0.f;
        if (k < TDIM && col < 602) {
            if (col < 100)      val = Wq[col * TDIM + k];
            else if (col < 200) val = Wk[(col - 100) * TDIM + k];
            else if (col < 300) val = Wv[(col - 200) * TDIM + k];
            else if (col < 400) val = Ws[(col - 300) * TDIM + k];
            else if (col < 501) {
                int j = col - 400;
                for (int d = 0; d < HALFC; ++d)
                    val = fmaf(Wq[d * TDIM + k], We[d * EDGED + j], val);
            } else {
                int j = col - 501;
                for (int d = HALFC; d < TDIM; ++d)
                    val = fmaf(Wq[d * TDIM + k], We[d * EDGED + j], val);
            }
        }
        __half h = __float2half(val);
        WTh[t] = h;
        WTl[t] = __float2half(val - __half2float(h));
    } else {
        int i = t - NCOLP * KPAD;
        if (i < NCOLP) {
            float b = 0.f;
            if (i < 100)      b = bq[i];
            else if (i < 200) b = bk[i - 100];
            else if (i < 300) b = bv[i - 200];
            else if (i < 400) b = bs[i - 300];
            else if (i < 501) {
                int j = i - 400;
                for (int d = 0; d < HALFC; ++d) b = fmaf(bq[d], We[d * EDGED + j], b);
            } else if (i < 602) {
                int j = i - 501;
                for (int d = HALFC; d < TDIM; ++d) b = fmaf(bq[d], We[d * EDGED + j], b);
            }
            bias_all[i] = b;
        }
    }
}

// ---------------- CSR build ----------------
__global__ void k_count(const int* __restrict__ ei, int E, int* __restrict__ deg) {
    int e = blockIdx.x * blockDim.x + threadIdx.x;
    if (e < E) atomicAdd(&deg[ei[E + e]], 1);
}

__global__ void k_scan1(const int* __restrict__ deg, int N, int* __restrict__ bsum) {
    __shared__ int s[SCB];
    int t = threadIdx.x, i = blockIdx.x * SCB + t;
    s[t] = (i < N) ? deg[i] : 0;
    __syncthreads();
    for (int st = SCB / 2; st > 0; st >>= 1) {
        if (t < st) s[t] += s[t + st];
        __syncthreads();
    }
    if (t == 0) bsum[blockIdx.x] = s[0];
}

__global__ void k_scan2(const int* __restrict__ bsum, int nb, int* __restrict__ bbase) {
    __shared__ int s[512];
    int t = threadIdx.x;
    int v = (t < nb) ? bsum[t] : 0;
    s[t] = v;
    __syncthreads();
    for (int st = 1; st < 512; st <<= 1) {
        int x = (t >= st) ? s[t - st] : 0;
        __syncthreads();
        s[t] += x;
        __syncthreads();
    }
    if (t < nb) bbase[t] = s[t] - v;   // exclusive
}

__global__ void k_scan3(const int* __restrict__ deg, int N,
                        const int* __restrict__ bbase,
                        int* __restrict__ off, int* __restrict__ cursor) {
    __shared__ int s[SCB];
    int t = threadIdx.x, i = blockIdx.x * SCB + t;
    int v = (i < N) ? deg[i] : 0;
    s[t] = v;
    __syncthreads();
    for (int st = 1; st < SCB; st <<= 1) {
        int x = (t >= st) ? s[t - st] : 0;
        __syncthreads();
        s[t] += x;
        __syncthreads();
    }
    if (i < N) {
        int o = bbase[blockIdx.x] + s[t] - v;
        off[i] = o;
        cursor[i] = o;
    }
}

__global__ void k_fill(const int* __restrict__ ei, int E,
                       int* __restrict__ cursor, int* __restrict__ elist) {
    int e = blockIdx.x * blockDim.x + threadIdx.x;
    if (e >= E) return;
    int pos = atomicAdd(&cursor[ei[E + e]], 1);
    elist[pos] = e;
}

// ---------------- K1: MFMA fused node GEMM (split-fp16) ----------------
__global__ __launch_bounds__(256) void k_gemm(
    const float* __restrict__ z,
    const __half* __restrict__ WTh, const __half* __restrict__ WTl,
    const float* __restrict__ bias_all,
    __half* __restrict__ qh, __half* __restrict__ kh, __half* __restrict__ vh,
    float* __restrict__ zbuf, __half* __restrict__ qW0h, __half* __restrict__ qW1h,
    int N)
{
    __shared__ __half zsh[64][KPAD];
    __shared__ __half zsl[64][KPAD];
    int tid = threadIdx.x;
    int m0 = blockIdx.x * 64;
    int cols0 = blockIdx.y * 160;

    for (int idx = tid; idx < 64 * 25; idx += 256) {
        int row = idx / 25, c4 = idx % 25;
        int node = m0 + row;
        float4 zz = (node < N) ? ((const float4*)(z + (size_t)node * TDIM))[c4]
                               : make_float4(0.f, 0.f, 0.f, 0.f);
        float f[4] = {zz.x, zz.y, zz.z, zz.w};
#pragma unroll
        for (int j = 0; j < 4; ++j) {
            __half h = __float2half(f[j]);
            zsh[row][c4 * 4 + j] = h;
            zsl[row][c4 * 4 + j] = __float2half(f[j] - __half2float(h));
        }
    }
    for (int idx = tid; idx < 64 * (KPAD - TDIM); idx += 256) {
        int row = idx / (KPAD - TDIM), k = TDIM + idx % (KPAD - TDIM);
        zsh[row][k] = __half(0.f);
        zsl[row][k] = __half(0.f);
    }
    __syncthreads();

    int wave = tid >> 6, lane = tid & 63;
    int arow = wave * 16 + (lane & 15);
    int kgrp = (lane >> 4) * 8;
    f32x4 acc[10];
#pragma unroll
    for (int c = 0; c < 10; ++c) acc[c] = f32x4{0.f, 0.f, 0.f, 0.f};

#pragma unroll
    for (int kk = 0; kk < KPAD; kk += 32) {
        f16x8 ah = *(const f16x8*)&zsh[arow][kk + kgrp];
        f16x8 al = *(const f16x8*)&zsl[arow][kk + kgrp];
#pragma unroll
        for (int c = 0; c < 10; ++c) {
            int col = cols0 + c * 16 + (lane & 15);
            f16x8 bh = *(const f16x8*)&WTh[col * KPAD + kk + kgrp];
            f16x8 bl = *(const f16x8*)&WTl[col * KPAD + kk + kgrp];
            acc[c] = __builtin_amdgcn_mfma_f32_16x16x32_f16(ah, bh, acc[c], 0, 0, 0);
            acc[c] = __builtin_amdgcn_mfma_f32_16x16x32_f16(al, bh, acc[c], 0, 0, 0);
            acc[c] = __builtin_amdgcn_mfma_f32_16x16x32_f16(ah, bl, acc[c], 0, 0, 0);
        }
    }

#pragma unroll
    for (int c = 0; c < 10; ++c) {
        int col = cols0 + c * 16 + (lane & 15);
        if (col >= 602) continue;
        float bias = bias_all[col];
#pragma unroll
        for (int r = 0; r < 4; ++r) {
            int node = m0 + wave * 16 + (lane >> 4) * 4 + r;
            if (node >= N) continue;
            float val = acc[c][r] + bias;
            if (col < 100)      qh[(size_t)node * TDIM + col]         = __float2half(val);
            else if (col < 200) kh[(size_t)node * TDIM + col - 100]   = __float2half(val);
            else if (col < 300) vh[(size_t)node * TDIM + col - 200]   = __float2half(val);
            else if (col < 400) zbuf[(size_t)node * TDIM + col - 300] = val;
            else if (col < 501) qW0h[(size_t)node * EDGEP + col - 400] = __float2half(val);
            else                qW1h[(size_t)node * EDGEP + col - 501] = __float2half(val);
        }
    }
}

// ---------------- K2a: edge-parallel logits ----------------
// logit_h = qWe_h[dst] . edge_attr + q[dst] . k_h[src];  aux = {rel, m, a0, a1}
__global__ __launch_bounds__(256) void k_logit(
    const float* __restrict__ lu, const float* __restrict__ tt,
    const float* __restrict__ msg,
    const float* __restrict__ tw, const float* __restrict__ tb,
    const __half* __restrict__ qh, const __half* __restrict__ kh,
    const __half* __restrict__ qW0h, const __half* __restrict__ qW1h,
    const int* __restrict__ ei, int E, float4* __restrict__ aux)
{
    const float INVS = 0.14142135623730951f;   // 1/sqrt(50)
    int e = blockIdx.x * 256 + threadIdx.x;
    if (e >= E) return;
    int sn = ei[e], dn = ei[E + e];
    float rel = lu[sn] - tt[e];
    float m = msg[e];

    const __half2* q2 = (const __half2*)(qh + (size_t)dn * TDIM);
    const __half2* k2 = (const __half2*)(kh + (size_t)sn * TDIM);
    float qk0 = 0.f, qk1 = 0.f;
#pragma unroll
    for (int c = 0; c < 25; ++c) {
        float2 qq = __half22float2(q2[c]);
        float2 kk = __half22float2(k2[c]);
        qk0 = fmaf(qq.x, kk.x, qk0);
        qk0 = fmaf(qq.y, kk.y, qk0);
    }
#pragma unroll
    for (int c = 25; c < 50; ++c) {
        float2 qq = __half22float2(q2[c]);
        float2 kk = __half22float2(k2[c]);
        qk1 = fmaf(qq.x, kk.x, qk1);
        qk1 = fmaf(qq.y, kk.y, qk1);
    }

    const __half2* w02 = (const __half2*)(qW0h + (size_t)dn * EDGEP);
    const __half2* w12 = (const __half2*)(qW1h + (size_t)dn * EDGEP);
    float l0 = qk0, l1 = qk1;
#pragma unroll 5
    for (int c = 0; c < 50; ++c) {
        float cv0 = __cosf(fmaf(rel, tw[2 * c], tb[2 * c]));
        float cv1 = __cosf(fmaf(rel, tw[2 * c + 1], tb[2 * c + 1]));
        float2 w0 = __half22float2(w02[c]);
        float2 w1 = __half22float2(w12[c]);
        l0 = fmaf(w0.x, cv0, l0); l0 = fmaf(w0.y, cv1, l0);
        l1 = fmaf(w1.x, cv0, l1); l1 = fmaf(w1.y, cv1, l1);
    }
    l0 = fmaf(__half2float(qW0h[(size_t)dn * EDGEP + 100]), m, l0);
    l1 = fmaf(__half2float(qW1h[(size_t)dn * EDGEP + 100]), m, l1);

    aux[e] = make_float4(rel, m, __expf(l0 * INVS), __expf(l1 * INVS));
}

// ---------------- K2b: wave-per-node CSR gather ----------------
__global__ __launch_bounds__(256) void k_gather(
    const float* __restrict__ tw, const float* __restrict__ tb,
    const __half* __restrict__ vh, const float* __restrict__ WeT,
    const int* __restrict__ ei, const int* __restrict__ elist,
    const int* __restrict__ off, const int* __restrict__ deg,
    const float4* __restrict__ aux, int N, float* __restrict__ zbuf)
{
    int lane = threadIdx.x & 63;
    int wid = __builtin_amdgcn_readfirstlane(threadIdx.x >> 6);
    int n = blockIdx.x * 4 + wid;
    if (n >= N) return;
    int dg = deg[n];
    if (dg == 0) return;                       // zbuf stays = skip
    int nb = off[n];

    const int dA = lane, dB = 64 + lane;
    const bool outB = (lane < 36);
    const bool cosB = (lane < 36);
    const bool msgB = (lane == 36);
    const bool h0A = (dA < HALFC);

    float twA = tw[dA], tbA = tb[dA];
    float twB = cosB ? tw[dB] : 0.f, tbB = cosB ? tb[dB] : 0.f;

    float den0 = 0.f, den1 = 0.f;
    float vsA = 0.f, vsB = 0.f;
    float c0A = 0.f, c0B = 0.f, c1A = 0.f, c1B = 0.f;

    for (int i = 0; i < dg; ++i) {
        int eid = __builtin_amdgcn_readfirstlane(elist[nb + i]);
        int sn  = __builtin_amdgcn_readfirstlane(ei[eid]);
        float4 ax = aux[eid];                   // {rel, m, a0, a1} wave-uniform
        float cvA = __cosf(fmaf(ax.x, twA, tbA));
        float cvB = cosB ? __cosf(fmaf(ax.x, twB, tbB)) : (msgB ? ax.y : 0.f);
        size_t sb = (size_t)sn * TDIM;
        float vA = __half2float(vh[sb + dA]);
        float vB = outB ? __half2float(vh[sb + dB]) : 0.f;
        den0 += ax.z; den1 += ax.w;
        vsA = fmaf(h0A ? ax.z : ax.w, vA, vsA);
        vsB = fmaf(ax.w, vB, vsB);
        c0A = fmaf(ax.z, cvA, c0A);  c0B = fmaf(ax.z, cvB, c0B);
        c1A = fmaf(ax.w, cvA, c1A);  c1B = fmaf(ax.w, cvB, c1B);
    }

    float accA = vsA, accB = vsB;
#pragma unroll 4
    for (int j = 0; j < 64; ++j) {
        float b0 = __shfl(c0A, j);
        float b1 = __shfl(c1A, j);
        float wA = WeT[j * TDIM + dA];
        float wB = outB ? WeT[j * TDIM + dB] : 0.f;
        accA = fmaf(wA, h0A ? b0 : b1, accA);
        accB = fmaf(wB, b1, accB);
    }
#pragma unroll 4
    for (int j = 64; j < EDGED; ++j) {
        float b0 = __shfl(c0B, j - 64);
        float b1 = __shfl(c1B, j - 64);
        float wA = WeT[j * TDIM + dA];
        float wB = outB ? WeT[j * TDIM + dB] : 0.f;
        accA = fmaf(wA, h0A ? b0 : b1, accA);
        accB = fmaf(wB, b1, accB);
    }
    float inv0 = 1.f / den0, inv1 = 1.f / den1;
    size_t ob = (size_t)n * TDIM;
    zbuf[ob + dA] += accA * (h0A ? inv0 : inv1);
    if (outB) zbuf[ob + dB] += accB * inv1;
}

// ---------------- K4: link predictor ----------------
#define LPB 64
__global__ __launch_bounds__(256) void k_link(
    const float* __restrict__ zout,
    const float* __restrict__ Wsr, const float* __restrict__ bsr,
    const float* __restrict__ Wds, const float* __restrict__ bds,
    const float* __restrict__ Wf, const float* __restrict__ bf,
    const int* __restrict__ assoc, const int* __restrict__ src,
    const int* __restrict__ dst, int B, float* __restrict__ outp)
{
    __shared__ float zs[LPB][EDGED];
    __shared__ float zd[LPB][EDGED];
    __shared__ int rowS[LPB], rowD[LPB];
    int tid = threadIdx.x;
    int l0 = blockIdx.x * LPB;
    if (tid < LPB) {
        int li = l0 + tid;
        rowS[tid] = (li < B) ? assoc[src[li]] : 0;
        rowD[tid] = (li < B) ? assoc[dst[li]] : 0;
    }
    __syncthreads();
    for (int i = tid; i < LPB * TDIM; i += 256) {
        int l = i / TDIM, d2 = i - l * TDIM;
        zs[l][d2] = zout[(size_t)rowS[l] * TDIM + d2];
        zd[l][d2] = zout[(size_t)rowD[l] * TDIM + d2];
    }
    __syncthreads();
    int l = tid >> 2, qt = tid & 3;
    float part = 0.f;
    for (int oo = 0; oo < 25; ++oo) {
        int out = qt * 25 + oo;
        const float4* ws4 = (const float4*)(Wsr + out * TDIM);
        const float4* wd4 = (const float4*)(Wds + out * TDIM);
        float accS = 0.f, accD = 0.f;
#pragma unroll
        for (int j = 0; j < 25; ++j) {
            float4 a = ws4[j];
            float4 b = wd4[j];
            accS = fmaf(a.x, zs[l][4*j+0], accS); accS = fmaf(a.y, zs[l][4*j+1], accS);
            accS = fmaf(a.z, zs[l][4*j+2], accS); accS = fmaf(a.w, zs[l][4*j+3], accS);
            accD = fmaf(b.x, zd[l][4*j+0], accD); accD = fmaf(b.y, zd[l][4*j+1], accD);
            accD = fmaf(b.z, zd[l][4*j+2], accD); accD = fmaf(b.w, zd[l][4*j+3], accD);
        }
        float h = accS + accD + bsr[out] + bds[out];
        h = fmaxf(h, 0.f);
        part = fmaf(Wf[out], h, part);
    }
    part += __shfl_xor(part, 1);
    part += __shfl_xor(part, 2);
    int li = l0 + l;
    if (qt == 0 && li < B) outp[li] = part + bf[0];
}

extern "C" void kernel_launch(void* const* d_in, const int* in_sizes, int n_in,
                              void* d_out, int out_size, void* d_ws, size_t ws_size,
                              hipStream_t stream)
{
    const float* z   = (const float*)d_in[0];
    const float* lu  = (const float*)d_in[1];
    const float* tt  = (const float*)d_in[2];
    const float* msg = (const float*)d_in[3];
    const float* tw  = (const float*)d_in[4];
    const float* tb  = (const float*)d_in[5];
    const float* Wq  = (const float*)d_in[6];  const float* bq  = (const float*)d_in[7];
    const float* Wk  = (const float*)d_in[8];  const float* bk  = (const float*)d_in[9];
    const float* Wv  = (const float*)d_in[10]; const float* bv  = (const float*)d_in[11];
    const float* We  = (const float*)d_in[12];
    const float* Wsk = (const float*)d_in[13]; const float* bsk = (const float*)d_in[14];
    const float* Wsr = (const float*)d_in[15]; const float* bsr = (const float*)d_in[16];
    const float* Wds = (const float*)d_in[17]; const float* bds = (const float*)d_in[18];
    const float* Wf  = (const float*)d_in[19]; const float* bf  = (const float*)d_in[20];
    const int* n_id  = (const int*)d_in[21];
    const int* srcI  = (const int*)d_in[22];
    const int* dstI  = (const int*)d_in[23];
    const int* ei    = (const int*)d_in[24];

    int N = in_sizes[0] / TDIM;   // 100000
    int E = in_sizes[2];          // 500000
    int B = in_sizes[22];         // 20000
    const size_t NUM_NODES = 1000000;
    int nblk = (N + SCB - 1) / SCB;  // 391

    char* w = (char*)d_ws;
    int*    assoc = (int*)w;    w += NUM_NODES * sizeof(int);          // 4.0 MB
    float4* aux   = (float4*)w; w += (size_t)E * 16;                   // 8.0 MB
    __half* qh    = (__half*)w; w += (size_t)N * TDIM * 2;             // 20 MB
    __half* kh    = (__half*)w; w += (size_t)N * TDIM * 2;             // 20 MB
    __half* vh    = (__half*)w; w += (size_t)N * TDIM * 2;             // 20 MB
    float*  zbuf  = (float*)w;  w += (size_t)N * TDIM * 4;             // 40 MB
    __half* qW0h  = (__half*)w; w += (size_t)N * EDGEP * 2;            // 20.8 MB
    __half* qW1h  = (__half*)w; w += (size_t)N * EDGEP * 2;            // 20.8 MB
    float*  WeT   = (float*)w;  w += WET_PAD * 4;                      // 40 KB
    __half* WTh   = (__half*)w; w += (size_t)NCOLP * KPAD * 2;         // 160 KB
    __half* WTl   = (__half*)w; w += (size_t)NCOLP * KPAD * 2;         // 160 KB
    float*  biasA = (float*)w;  w += NCOLP * 4;                        // 2.5 KB
    int*    deg   = (int*)w;    w += (size_t)N * sizeof(int);          // 0.4 MB
    int*    off   = (int*)w;    w += (size_t)N * sizeof(int);          // 0.4 MB
    int*    curs  = (int*)w;    w += (size_t)N * sizeof(int);          // 0.4 MB
    int*    bsum  = (int*)w;    w += 512 * sizeof(int);
    int*    bbase = (int*)w;    w += 512 * sizeof(int);
    int*    elist = (int*)w;    w += (size_t)E * sizeof(int);          // 2 MB
    // total ~157 MB

    hipLaunchKernelGGL(k_prep, dim3((N + 255) / 256), dim3(256), 0, stream,
                       n_id, N, We, assoc, deg, WeT);
    hipLaunchKernelGGL(k_precomp2, dim3((NCOLP * KPAD + NCOLP + 255) / 256), dim3(256), 0, stream,
                       Wq, bq, Wk, bk, Wv, bv, Wsk, bsk, We, WTh, WTl, biasA);
    hipLaunchKernelGGL(k_count, dim3((E + 255) / 256), dim3(256), 0, stream, ei, E, deg);
    hipLaunchKernelGGL(k_scan1, dim3(nblk), dim3(SCB), 0, stream, deg, N, bsum);
    hipLaunchKernelGGL(k_scan2, dim3(1), dim3(512), 0, stream, bsum, nblk, bbase);
    hipLaunchKernelGGL(k_scan3, dim3(nblk), dim3(SCB), 0, stream, deg, N, bbase, off, curs);
    hipLaunchKernelGGL(k_fill, dim3((E + 255) / 256), dim3(256), 0, stream, ei, E, curs, elist);
    hipLaunchKernelGGL(k_gemm, dim3((N + 63) / 64, 4), dim3(256), 0, stream,
                       z, WTh, WTl, biasA, qh, kh, vh, zbuf, qW0h, qW1h, N);
    hipLaunchKernelGGL(k_logit, dim3((E + 255) / 256), dim3(256), 0, stream,
                       lu, tt, msg, tw, tb, qh, kh, qW0h, qW1h, ei, E, aux);
    hipLaunchKernelGGL(k_gather, dim3((N + 3) / 4), dim3(256), 0, stream,
                       tw, tb, vh, WeT, ei, elist, off, deg, aux, N, zbuf);
    hipLaunchKernelGGL(k_link, dim3((B + LPB - 1) / LPB), dim3(256), 0, stream,
                       zbuf, Wsr, bsr, Wds, bds, Wf, bf, assoc, srcI, dstI, B,
                       (float*)d_out);
}

// Round 6
// 1257.653 us; speedup vs baseline: 1.1653x; 1.1653x over previous
//
#include <hip/hip_runtime.h>
#include <hip/hip_fp16.h>
#include <math.h>

#define TDIM 100      // D
#define EDGED 101     // D + MSG_DIM
#define EDGEP 104     // padded qW row stride (halfs)
#define HALFC 50      // per-head channels
#define NCOLP 640     // padded fused-output columns (602 real)
#define KPAD 128      // padded K for node GEMM
#define NCOL2 112     // padded out cols for CW GEMM (100 real)
#define K2P 224       // padded K for CW GEMM (202 real)
#define CWS 204       // CW row stride (floats)
#define SCB 256

typedef __attribute__((ext_vector_type(8))) _Float16 f16x8;
typedef __attribute__((ext_vector_type(4))) float f32x4;

// ---------------- K0: assoc + deg zero ----------------
__global__ void k_prep(const int* __restrict__ n_id, int N,
                       int* __restrict__ assoc, int* __restrict__ deg) {
    int i = blockIdx.x * blockDim.x + threadIdx.x;
    if (i < N) {
        assoc[n_id[i]] = i;
        deg[i] = 0;
    }
}

// ---------------- K0a: fused weights (WT for node GEMM, WT2 for CW GEMM) ------
__global__ __launch_bounds__(256) void k_precomp2(
    const float* __restrict__ Wq, const float* __restrict__ bq,
    const float* __restrict__ Wk, const float* __restrict__ bk,
    const float* __restrict__ Wv, const float* __restrict__ bv,
    const float* __restrict__ Ws, const float* __restrict__ bs,
    const float* __restrict__ We,
    __half* __restrict__ WTh, __half* __restrict__ WTl,
    __half* __restrict__ WT2h, __half* __restrict__ WT2l,
    float* __restrict__ bias_all)
{
    int t = blockIdx.x * blockDim.x + threadIdx.x;
    if (t < NCOLP * KPAD) {
        int col = t >> 7, k = t & 127;
        float val = 0.f;
        if (k < TDIM && col < 602) {
            if (col < 100)      val = Wq[col * TDIM + k];
            else if (col < 200) val = Wk[(col - 100) * TDIM + k];
            else if (col < 300) val = Wv[(col - 200) * TDIM + k];
            else if (col < 400) val = Ws[(col - 300) * TDIM + k];
            else if (col < 501) {
                int j = col - 400;
                for (int d = 0; d < HALFC; ++d)
                    val = fmaf(Wq[d * TDIM + k], We[d * EDGED + j], val);
            } else {
                int j = col - 501;
                for (int d = HALFC; d < TDIM; ++d)
                    val = fmaf(Wq[d * TDIM + k], We[d * EDGED + j], val);
            }
        }
        __half h = __float2half(val);
        WTh[t] = h;
        WTl[t] = __float2half(val - __half2float(h));
        return;
    }
    int t2 = t - NCOLP * KPAD;
    if (t2 < NCOL2 * K2P) {
        int col = t2 / K2P, k = t2 - (t2 / K2P) * K2P;
        float val = 0.f;
        if (col < TDIM) {
            if (k < EDGED && col < HALFC)                      // head0 block
                val = We[col * EDGED + k];
            else if (k >= EDGED && k < 2 * EDGED && col >= HALFC)  // head1 block
                val = We[col * EDGED + (k - EDGED)];
        }
        __half h = __float2half(val);
        WT2h[t2] = h;
        WT2l[t2] = __float2half(val - __half2float(h));
        return;
    }
    int i = t2 - NCOL2 * K2P;
    if (i < NCOLP) {
        float b = 0.f;
        if (i < 100)      b = bq[i];
        else if (i < 200) b = bk[i - 100];
        else if (i < 300) b = bv[i - 200];
        else if (i < 400) b = bs[i - 300];
        else if (i < 501) {
            int j = i - 400;
            for (int d = 0; d < HALFC; ++d) b = fmaf(bq[d], We[d * EDGED + j], b);
        } else if (i < 602) {
            int j = i - 501;
            for (int d = HALFC; d < TDIM; ++d) b = fmaf(bq[d], We[d * EDGED + j], b);
        }
        bias_all[i] = b;
    }
}

// ---------------- CSR build ----------------
__global__ void k_count(const int* __restrict__ ei, int E, int* __restrict__ deg) {
    int e = blockIdx.x * blockDim.x + threadIdx.x;
    if (e < E) atomicAdd(&deg[ei[E + e]], 1);
}

__global__ void k_scan1(const int* __restrict__ deg, int N, int* __restrict__ bsum) {
    __shared__ int s[SCB];
    int t = threadIdx.x, i = blockIdx.x * SCB + t;
    s[t] = (i < N) ? deg[i] : 0;
    __syncthreads();
    for (int st = SCB / 2; st > 0; st >>= 1) {
        if (t < st) s[t] += s[t + st];
        __syncthreads();
    }
    if (t == 0) bsum[blockIdx.x] = s[0];
}

__global__ void k_scan2(const int* __restrict__ bsum, int nb, int* __restrict__ bbase) {
    __shared__ int s[512];
    int t = threadIdx.x;
    int v = (t < nb) ? bsum[t] : 0;
    s[t] = v;
    __syncthreads();
    for (int st = 1; st < 512; st <<= 1) {
        int x = (t >= st) ? s[t - st] : 0;
        __syncthreads();
        s[t] += x;
        __syncthreads();
    }
    if (t < nb) bbase[t] = s[t] - v;   // exclusive
}

__global__ void k_scan3(const int* __restrict__ deg, int N,
                        const int* __restrict__ bbase,
                        int* __restrict__ off, int* __restrict__ cursor) {
    __shared__ int s[SCB];
    int t = threadIdx.x, i = blockIdx.x * SCB + t;
    int v = (i < N) ? deg[i] : 0;
    s[t] = v;
    __syncthreads();
    for (int st = 1; st < SCB; st <<= 1) {
        int x = (t >= st) ? s[t - st] : 0;
        __syncthreads();
        s[t] += x;
        __syncthreads();
    }
    if (i < N) {
        int o = bbase[blockIdx.x] + s[t] - v;
        off[i] = o;
        cursor[i] = o;
    }
}

// fill: scatter per-edge data into dst-sorted position
__global__ void k_fill2(const int* __restrict__ ei,
                        const float* __restrict__ lu, const float* __restrict__ tt,
                        const float* __restrict__ msg, int E,
                        int* __restrict__ cursor,
                        int* __restrict__ esrcs, int* __restrict__ edst,
                        float2* __restrict__ aux_rm) {
    int e = blockIdx.x * blockDim.x + threadIdx.x;
    if (e >= E) return;
    int sn = ei[e], dn = ei[E + e];
    int pos = atomicAdd(&cursor[dn], 1);
    esrcs[pos] = sn;
    edst[pos] = dn;
    aux_rm[pos] = make_float2(lu[sn] - tt[e], msg[e]);
}

// ---------------- K1: MFMA fused node GEMM (split-fp16) ----------------
__global__ __launch_bounds__(256) void k_gemm(
    const float* __restrict__ z,
    const __half* __restrict__ WTh, const __half* __restrict__ WTl,
    const float* __restrict__ bias_all,
    __half* __restrict__ qh, __half* __restrict__ kh, __half* __restrict__ vh,
    float* __restrict__ zbuf, __half* __restrict__ qW0h, __half* __restrict__ qW1h,
    int N)
{
    __shared__ __half zsh[64][KPAD];
    __shared__ __half zsl[64][KPAD];
    int tid = threadIdx.x;
    int m0 = blockIdx.x * 64;
    int cols0 = blockIdx.y * 160;

    for (int idx = tid; idx < 64 * 25; idx += 256) {
        int row = idx / 25, c4 = idx % 25;
        int node = m0 + row;
        float4 zz = (node < N) ? ((const float4*)(z + (size_t)node * TDIM))[c4]
                               : make_float4(0.f, 0.f, 0.f, 0.f);
        float f[4] = {zz.x, zz.y, zz.z, zz.w};
#pragma unroll
        for (int j = 0; j < 4; ++j) {
            __half h = __float2half(f[j]);
            zsh[row][c4 * 4 + j] = h;
            zsl[row][c4 * 4 + j] = __float2half(f[j] - __half2float(h));
        }
    }
    for (int idx = tid; idx < 64 * (KPAD - TDIM); idx += 256) {
        int row = idx / (KPAD - TDIM), k = TDIM + idx % (KPAD - TDIM);
        zsh[row][k] = __half(0.f);
        zsl[row][k] = __half(0.f);
    }
    __syncthreads();

    int wave = tid >> 6, lane = tid & 63;
    int arow = wave * 16 + (lane & 15);
    int kgrp = (lane >> 4) * 8;
    f32x4 acc[10];
#pragma unroll
    for (int c = 0; c < 10; ++c) acc[c] = f32x4{0.f, 0.f, 0.f, 0.f};

#pragma unroll
    for (int kk = 0; kk < KPAD; kk += 32) {
        f16x8 ah = *(const f16x8*)&zsh[arow][kk + kgrp];
        f16x8 al = *(const f16x8*)&zsl[arow][kk + kgrp];
#pragma unroll
        for (int c = 0; c < 10; ++c) {
            int col = cols0 + c * 16 + (lane & 15);
            f16x8 bh = *(const f16x8*)&WTh[col * KPAD + kk + kgrp];
            f16x8 bl = *(const f16x8*)&WTl[col * KPAD + kk + kgrp];
            acc[c] = __builtin_amdgcn_mfma_f32_16x16x32_f16(ah, bh, acc[c], 0, 0, 0);
            acc[c] = __builtin_amdgcn_mfma_f32_16x16x32_f16(al, bh, acc[c], 0, 0, 0);
            acc[c] = __builtin_amdgcn_mfma_f32_16x16x32_f16(ah, bl, acc[c], 0, 0, 0);
        }
    }

#pragma unroll
    for (int c = 0; c < 10; ++c) {
        int col = cols0 + c * 16 + (lane & 15);
        if (col >= 602) continue;
        float bias = bias_all[col];
#pragma unroll
        for (int r = 0; r < 4; ++r) {
            int node = m0 + wave * 16 + (lane >> 4) * 4 + r;
            if (node >= N) continue;
            float val = acc[c][r] + bias;
            if (col < 100)      qh[(size_t)node * TDIM + col]          = __float2half(val);
            else if (col < 200) kh[(size_t)node * TDIM + col - 100]    = __float2half(val);
            else if (col < 300) vh[(size_t)node * TDIM + col - 200]    = __float2half(val);
            else if (col < 400) zbuf[(size_t)node * TDIM + col - 300]  = val;
            else if (col < 501) qW0h[(size_t)node * EDGEP + col - 400] = __float2half(val);
            else                qW1h[(size_t)node * EDGEP + col - 501] = __float2half(val);
        }
    }
}

// ---------------- K2a: edge-parallel logits (dst-sorted order) ----------------
__global__ __launch_bounds__(256) void k_logit2(
    const float2* __restrict__ aux_rm,
    const int* __restrict__ esrcs, const int* __restrict__ edst,
    const float* __restrict__ tw, const float* __restrict__ tb,
    const __half* __restrict__ qh, const __half* __restrict__ kh,
    const __half* __restrict__ qW0h, const __half* __restrict__ qW1h,
    int E, float4* __restrict__ aux_s)
{
    const float INVS = 0.14142135623730951f;   // 1/sqrt(50)
    int p = blockIdx.x * 256 + threadIdx.x;
    if (p >= E) return;
    float2 rm = aux_rm[p];
    int sn = esrcs[p], dn = edst[p];
    float rel = rm.x, m = rm.y;

    const __half2* q2 = (const __half2*)(qh + (size_t)dn * TDIM);
    const __half2* k2 = (const __half2*)(kh + (size_t)sn * TDIM);
    float qk0 = 0.f, qk1 = 0.f;
#pragma unroll
    for (int c = 0; c < 25; ++c) {
        float2 qq = __half22float2(q2[c]);
        float2 kk = __half22float2(k2[c]);
        qk0 = fmaf(qq.x, kk.x, qk0);
        qk0 = fmaf(qq.y, kk.y, qk0);
    }
#pragma unroll
    for (int c = 25; c < 50; ++c) {
        float2 qq = __half22float2(q2[c]);
        float2 kk = __half22float2(k2[c]);
        qk1 = fmaf(qq.x, kk.x, qk1);
        qk1 = fmaf(qq.y, kk.y, qk1);
    }

    const __half2* w02 = (const __half2*)(qW0h + (size_t)dn * EDGEP);
    const __half2* w12 = (const __half2*)(qW1h + (size_t)dn * EDGEP);
    float l0 = qk0, l1 = qk1;
#pragma unroll 5
    for (int c = 0; c < 50; ++c) {
        float cv0 = __cosf(fmaf(rel, tw[2 * c], tb[2 * c]));
        float cv1 = __cosf(fmaf(rel, tw[2 * c + 1], tb[2 * c + 1]));
        float2 w0 = __half22float2(w02[c]);
        float2 w1 = __half22float2(w12[c]);
        l0 = fmaf(w0.x, cv0, l0); l0 = fmaf(w0.y, cv1, l0);
        l1 = fmaf(w1.x, cv0, l1); l1 = fmaf(w1.y, cv1, l1);
    }
    l0 = fmaf(__half2float(qW0h[(size_t)dn * EDGEP + 100]), m, l0);
    l1 = fmaf(__half2float(qW1h[(size_t)dn * EDGEP + 100]), m, l1);

    aux_s[p] = make_float4(rel, m, __expf(l0 * INVS), __expf(l1 * INVS));
}

// ---------------- K2b: 6-waves-per-node segment sums (no shfl, no epilogue) ---
// role 0/1: vsum over d (2 slots); role 2..5: cw for (head, j-half).
// Writes zbuf += vsum/den and CW[n][202] = cw_h/den_h (zeros when deg==0).
__global__ __launch_bounds__(256) void k_gather3(
    const float* __restrict__ tw, const float* __restrict__ tb,
    const __half* __restrict__ vh, const int* __restrict__ esrcs,
    const float4* __restrict__ aux_s,
    const int* __restrict__ off, const int* __restrict__ deg,
    int N, float* __restrict__ zbuf, float* __restrict__ CW)
{
    int gw = (blockIdx.x * 256 + threadIdx.x) >> 6;
    int lane = threadIdx.x & 63;
    int n = gw / 6;
    int role = gw - n * 6;
    if (n >= N) return;
    int dg = deg[n], nb = off[n];

    if (role < 2) {
        int d = role * 64 + lane;
        bool act = d < TDIM;
        bool h1 = d >= HALFC;
        float acc = 0.f, den = 0.f;
        for (int i = 0; i < dg; ++i) {
            float4 ax = aux_s[nb + i];            // wave-uniform broadcast
            int sn = esrcs[nb + i];               // wave-uniform
            float a = h1 ? ax.w : ax.z;
            den += a;
            if (act) acc = fmaf(a, __half2float(vh[(size_t)sn * TDIM + d]), acc);
        }
        if (dg > 0 && act) zbuf[(size_t)n * TDIM + d] += acc / den;
    } else {
        int r2 = role - 2;
        int hh = r2 >> 1, sub = r2 & 1;
        int j = sub * 64 + lane;
        bool act = j < EDGED;
        float twj = (j < TDIM) ? tw[j] : 0.f;
        float tbj = (j < TDIM) ? tb[j] : 0.f;
        float acc = 0.f, den = 0.f;
        for (int i = 0; i < dg; ++i) {
            float4 ax = aux_s[nb + i];
            float a = hh ? ax.w : ax.z;
            den += a;
            float cv = (j < TDIM) ? __cosf(fmaf(ax.x, twj, tbj)) : ax.y;
            acc = fmaf(a, cv, acc);
        }
        if (act) CW[(size_t)n * CWS + hh * EDGED + j] = (dg > 0) ? acc / den : 0.f;
    }
}

// ---------------- K3: MFMA CW GEMM: zbuf += CW[N x 202] * We2 ----------------
__global__ __launch_bounds__(256) void k_gemmCW(
    const float* __restrict__ CW,
    const __half* __restrict__ WT2h, const __half* __restrict__ WT2l,
    int N, float* __restrict__ zbuf)
{
    __shared__ __half ash[64][K2P];
    __shared__ __half asl[64][K2P];
    int tid = threadIdx.x;
    int m0 = blockIdx.x * 64;

    for (int idx = tid; idx < 64 * K2P; idx += 256) {
        int row = idx / K2P, k = idx - (idx / K2P) * K2P;
        int node = m0 + row;
        float vv = (k < 2 * EDGED && node < N) ? CW[(size_t)node * CWS + k] : 0.f;
        __half h = __float2half(vv);
        ash[row][k] = h;
        asl[row][k] = __float2half(vv - __half2float(h));
    }
    __syncthreads();

    int wave = tid >> 6, lane = tid & 63;
    int arow = wave * 16 + (lane & 15);
    int kgrp = (lane >> 4) * 8;
    f32x4 acc[7];
#pragma unroll
    for (int c = 0; c < 7; ++c) acc[c] = f32x4{0.f, 0.f, 0.f, 0.f};

#pragma unroll
    for (int kk = 0; kk < K2P; kk += 32) {
        f16x8 ah = *(const f16x8*)&ash[arow][kk + kgrp];
        f16x8 al = *(const f16x8*)&asl[arow][kk + kgrp];
#pragma unroll
        for (int c = 0; c < 7; ++c) {
            int col = c * 16 + (lane & 15);
            f16x8 bh = *(const f16x8*)&WT2h[col * K2P + kk + kgrp];
            f16x8 bl = *(const f16x8*)&WT2l[col * K2P + kk + kgrp];
            acc[c] = __builtin_amdgcn_mfma_f32_16x16x32_f16(ah, bh, acc[c], 0, 0, 0);
            acc[c] = __builtin_amdgcn_mfma_f32_16x16x32_f16(al, bh, acc[c], 0, 0, 0);
            acc[c] = __builtin_amdgcn_mfma_f32_16x16x32_f16(ah, bl, acc[c], 0, 0, 0);
        }
    }

#pragma unroll
    for (int c = 0; c < 7; ++c) {
        int col = c * 16 + (lane & 15);
        if (col >= TDIM) continue;
#pragma unroll
        for (int r = 0; r < 4; ++r) {
            int node = m0 + wave * 16 + (lane >> 4) * 4 + r;
            if (node >= N) continue;
            size_t o = (size_t)node * TDIM + col;
            zbuf[o] += acc[c][r];
        }
    }
}

// ---------------- K4: link predictor ----------------
#define LPB 64
__global__ __launch_bounds__(256) void k_link(
    const float* __restrict__ zout,
    const float* __restrict__ Wsr, const float* __restrict__ bsr,
    const float* __restrict__ Wds, const float* __restrict__ bds,
    const float* __restrict__ Wf, const float* __restrict__ bf,
    const int* __restrict__ assoc, const int* __restrict__ src,
    const int* __restrict__ dst, int B, float* __restrict__ outp)
{
    __shared__ float zs[LPB][EDGED];
    __shared__ float zd[LPB][EDGED];
    __shared__ int rowS[LPB], rowD[LPB];
    int tid = threadIdx.x;
    int l0 = blockIdx.x * LPB;
    if (tid < LPB) {
        int li = l0 + tid;
        rowS[tid] = (li < B) ? assoc[src[li]] : 0;
        rowD[tid] = (li < B) ? assoc[dst[li]] : 0;
    }
    __syncthreads();
    for (int i = tid; i < LPB * TDIM; i += 256) {
        int l = i / TDIM, d2 = i - l * TDIM;
        zs[l][d2] = zout[(size_t)rowS[l] * TDIM + d2];
        zd[l][d2] = zout[(size_t)rowD[l] * TDIM + d2];
    }
    __syncthreads();
    int l = tid >> 2, qt = tid & 3;
    float part = 0.f;
    for (int oo = 0; oo < 25; ++oo) {
        int out = qt * 25 + oo;
        const float4* ws4 = (const float4*)(Wsr + out * TDIM);
        const float4* wd4 = (const float4*)(Wds + out * TDIM);
        float accS = 0.f, accD = 0.f;
#pragma unroll
        for (int j = 0; j < 25; ++j) {
            float4 a = ws4[j];
            float4 b = wd4[j];
            accS = fmaf(a.x, zs[l][4*j+0], accS); accS = fmaf(a.y, zs[l][4*j+1], accS);
            accS = fmaf(a.z, zs[l][4*j+2], accS); accS = fmaf(a.w, zs[l][4*j+3], accS);
            accD = fmaf(b.x, zd[l][4*j+0], accD); accD = fmaf(b.y, zd[l][4*j+1], accD);
            accD = fmaf(b.z, zd[l][4*j+2], accD); accD = fmaf(b.w, zd[l][4*j+3], accD);
        }
        float h = accS + accD + bsr[out] + bds[out];
        h = fmaxf(h, 0.f);
        part = fmaf(Wf[out], h, part);
    }
    part += __shfl_xor(part, 1);
    part += __shfl_xor(part, 2);
    int li = l0 + l;
    if (qt == 0 && li < B) outp[li] = part + bf[0];
}

extern "C" void kernel_launch(void* const* d_in, const int* in_sizes, int n_in,
                              void* d_out, int out_size, void* d_ws, size_t ws_size,
                              hipStream_t stream)
{
    const float* z   = (const float*)d_in[0];
    const float* lu  = (const float*)d_in[1];
    const float* tt  = (const float*)d_in[2];
    const float* msg = (const float*)d_in[3];
    const float* tw  = (const float*)d_in[4];
    const float* tb  = (const float*)d_in[5];
    const float* Wq  = (const float*)d_in[6];  const float* bq  = (const float*)d_in[7];
    const float* Wk  = (const float*)d_in[8];  const float* bk  = (const float*)d_in[9];
    const float* Wv  = (const float*)d_in[10]; const float* bv  = (const float*)d_in[11];
    const float* We  = (const float*)d_in[12];
    const float* Wsk = (const float*)d_in[13]; const float* bsk = (const float*)d_in[14];
    const float* Wsr = (const float*)d_in[15]; const float* bsr = (const float*)d_in[16];
    const float* Wds = (const float*)d_in[17]; const float* bds = (const float*)d_in[18];
    const float* Wf  = (const float*)d_in[19]; const float* bf  = (const float*)d_in[20];
    const int* n_id  = (const int*)d_in[21];
    const int* srcI  = (const int*)d_in[22];
    const int* dstI  = (const int*)d_in[23];
    const int* ei    = (const int*)d_in[24];

    int N = in_sizes[0] / TDIM;   // 100000
    int E = in_sizes[2];          // 500000
    int B = in_sizes[22];         // 20000
    const size_t NUM_NODES = 1000000;
    int nblk = (N + SCB - 1) / SCB;

    char* w = (char*)d_ws;
    int*    assoc = (int*)w;    w += NUM_NODES * sizeof(int);          // 4.0 MB
    float2* auxrm = (float2*)w; w += (size_t)E * 8;                    // 4.0 MB
    float4* aux_s = (float4*)w; w += (size_t)E * 16;                   // 8.0 MB
    int*    esrcs = (int*)w;    w += (size_t)E * 4;                    // 2.0 MB
    int*    edst  = (int*)w;    w += (size_t)E * 4;                    // 2.0 MB
    __half* vh    = (__half*)w; w += (size_t)N * TDIM * 2;             // 20 MB
    float*  zbuf  = (float*)w;  w += (size_t)N * TDIM * 4;             // 40 MB
    // UNION: q/k/qW (GEMM+logit phase) aliased with CW (gather+gemmCW phase)
    char*   uni   = w;
    __half* qh    = (__half*)uni;
    __half* kh    = (__half*)(uni + (size_t)N * TDIM * 2);
    __half* qW0h  = (__half*)(uni + (size_t)N * TDIM * 4);
    __half* qW1h  = (__half*)(uni + (size_t)N * TDIM * 4 + (size_t)N * EDGEP * 2);
    float*  CW    = (float*)uni;                                       // N*204*4 = 81.6 MB
    w += (size_t)N * CWS * 4;                                          // 81.6 MB
    __half* WTh   = (__half*)w; w += (size_t)NCOLP * KPAD * 2;         // 160 KB
    __half* WTl   = (__half*)w; w += (size_t)NCOLP * KPAD * 2;         // 160 KB
    __half* WT2h  = (__half*)w; w += (size_t)NCOL2 * K2P * 2;          // 50 KB
    __half* WT2l  = (__half*)w; w += (size_t)NCOL2 * K2P * 2;          // 50 KB
    float*  biasA = (float*)w;  w += NCOLP * 4;
    int*    deg   = (int*)w;    w += (size_t)N * sizeof(int);
    int*    off   = (int*)w;    w += (size_t)N * sizeof(int);
    int*    curs  = (int*)w;    w += (size_t)N * sizeof(int);
    int*    bsum  = (int*)w;    w += 512 * sizeof(int);
    int*    bbase = (int*)w;    w += 512 * sizeof(int);
    // total ~163 MB

    hipLaunchKernelGGL(k_prep, dim3((N + 255) / 256), dim3(256), 0, stream,
                       n_id, N, assoc, deg);
    hipLaunchKernelGGL(k_precomp2,
                       dim3((NCOLP * KPAD + NCOL2 * K2P + NCOLP + 255) / 256), dim3(256), 0, stream,
                       Wq, bq, Wk, bk, Wv, bv, Wsk, bsk, We, WTh, WTl, WT2h, WT2l, biasA);
    hipLaunchKernelGGL(k_count, dim3((E + 255) / 256), dim3(256), 0, stream, ei, E, deg);
    hipLaunchKernelGGL(k_scan1, dim3(nblk), dim3(SCB), 0, stream, deg, N, bsum);
    hipLaunchKernelGGL(k_scan2, dim3(1), dim3(512), 0, stream, bsum, nblk, bbase);
    hipLaunchKernelGGL(k_scan3, dim3(nblk), dim3(SCB), 0, stream, deg, N, bbase, off, curs);
    hipLaunchKernelGGL(k_fill2, dim3((E + 255) / 256), dim3(256), 0, stream,
                       ei, lu, tt, msg, E, curs, esrcs, edst, auxrm);
    hipLaunchKernelGGL(k_gemm, dim3((N + 63) / 64, 4), dim3(256), 0, stream,
                       z, WTh, WTl, biasA, qh, kh, vh, zbuf, qW0h, qW1h, N);
    hipLaunchKernelGGL(k_logit2, dim3((E + 255) / 256), dim3(256), 0, stream,
                       auxrm, esrcs, edst, tw, tb, qh, kh, qW0h, qW1h, E, aux_s);
    hipLaunchKernelGGL(k_gather3, dim3(((size_t)N * 6 + 3) / 4), dim3(256), 0, stream,
                       tw, tb, vh, esrcs, aux_s, off, deg, N, zbuf, CW);
    hipLaunchKernelGGL(k_gemmCW, dim3((N + 63) / 64), dim3(256), 0, stream,
                       CW, WT2h, WT2l, N, zbuf);
    hipLaunchKernelGGL(k_link, dim3((B + LPB - 1) / LPB), dim3(256), 0, stream,
                       zbuf, Wsr, bsr, Wds, bds, Wf, bf, assoc, srcI, dstI, B,
                       (float*)d_out);
}

// Round 7
// 1117.899 us; speedup vs baseline: 1.3110x; 1.1250x over previous
//
#include <hip/hip_runtime.h>
#include <hip/hip_fp16.h>
#include <math.h>

#define TDIM 100      // D
#define EDGED 101     // D + MSG_DIM
#define EDGEP 104     // padded qW row stride (halfs)
#define HALFC 50      // per-head channels
#define NCOLP 640     // padded fused-output columns (602 real)
#define KPAD 128      // padded K for node GEMM (global WT stride)
#define LDSK 136      // LDS row stride for node GEMM (272B = 17*16B -> 2-way max)
#define NCOL2 112     // padded out cols for CW GEMM (100 real)
#define K2P 224       // padded K for CW GEMM (202 real, global WT2 stride)
#define K2L 232       // LDS row stride for CW GEMM (464B = 29*16B)
#define CWS 204       // CW row stride (floats)
#define SCB 256

typedef __attribute__((ext_vector_type(8))) _Float16 f16x8;
typedef __attribute__((ext_vector_type(4))) float f32x4;

// ---------------- K0: assoc + deg zero ----------------
__global__ void k_prep(const int* __restrict__ n_id, int N,
                       int* __restrict__ assoc, int* __restrict__ deg) {
    int i = blockIdx.x * blockDim.x + threadIdx.x;
    if (i < N) {
        assoc[n_id[i]] = i;
        deg[i] = 0;
    }
}

// ---------------- K0a: fused weights (WT for node GEMM, WT2 for CW GEMM) ------
__global__ __launch_bounds__(256) void k_precomp2(
    const float* __restrict__ Wq, const float* __restrict__ bq,
    const float* __restrict__ Wk, const float* __restrict__ bk,
    const float* __restrict__ Wv, const float* __restrict__ bv,
    const float* __restrict__ Ws, const float* __restrict__ bs,
    const float* __restrict__ We,
    __half* __restrict__ WTh, __half* __restrict__ WTl,
    __half* __restrict__ WT2h,
    float* __restrict__ bias_all)
{
    int t = blockIdx.x * blockDim.x + threadIdx.x;
    if (t < NCOLP * KPAD) {
        int col = t >> 7, k = t & 127;
        float val = 0.f;
        if (k < TDIM && col < 602) {
            if (col < 100)      val = Wq[col * TDIM + k];
            else if (col < 200) val = Wk[(col - 100) * TDIM + k];
            else if (col < 300) val = Wv[(col - 200) * TDIM + k];
            else if (col < 400) val = Ws[(col - 300) * TDIM + k];
            else if (col < 501) {
                int j = col - 400;
                for (int d = 0; d < HALFC; ++d)
                    val = fmaf(Wq[d * TDIM + k], We[d * EDGED + j], val);
            } else {
                int j = col - 501;
                for (int d = HALFC; d < TDIM; ++d)
                    val = fmaf(Wq[d * TDIM + k], We[d * EDGED + j], val);
            }
        }
        __half h = __float2half(val);
        WTh[t] = h;
        WTl[t] = __float2half(val - __half2float(h));
        return;
    }
    int t2 = t - NCOLP * KPAD;
    if (t2 < NCOL2 * K2P) {
        int col = t2 / K2P, k = t2 - (t2 / K2P) * K2P;
        float val = 0.f;
        if (col < TDIM) {
            if (k < EDGED && col < HALFC)                      // head0 block
                val = We[col * EDGED + k];
            else if (k >= EDGED && k < 2 * EDGED && col >= HALFC)  // head1 block
                val = We[col * EDGED + (k - EDGED)];
        }
        WT2h[t2] = __float2half(val);
        return;
    }
    int i = t2 - NCOL2 * K2P;
    if (i < NCOLP) {
        float b = 0.f;
        if (i < 100)      b = bq[i];
        else if (i < 200) b = bk[i - 100];
        else if (i < 300) b = bv[i - 200];
        else if (i < 400) b = bs[i - 300];
        else if (i < 501) {
            int j = i - 400;
            for (int d = 0; d < HALFC; ++d) b = fmaf(bq[d], We[d * EDGED + j], b);
        } else if (i < 602) {
            int j = i - 501;
            for (int d = HALFC; d < TDIM; ++d) b = fmaf(bq[d], We[d * EDGED + j], b);
        }
        bias_all[i] = b;
    }
}

// ---------------- CSR build ----------------
__global__ void k_count(const int* __restrict__ ei, int E, int* __restrict__ deg) {
    int e = blockIdx.x * blockDim.x + threadIdx.x;
    if (e < E) atomicAdd(&deg[ei[E + e]], 1);
}

__global__ void k_scan1(const int* __restrict__ deg, int N, int* __restrict__ bsum) {
    __shared__ int s[SCB];
    int t = threadIdx.x, i = blockIdx.x * SCB + t;
    s[t] = (i < N) ? deg[i] : 0;
    __syncthreads();
    for (int st = SCB / 2; st > 0; st >>= 1) {
        if (t < st) s[t] += s[t + st];
        __syncthreads();
    }
    if (t == 0) bsum[blockIdx.x] = s[0];
}

__global__ void k_scan2(const int* __restrict__ bsum, int nb, int* __restrict__ bbase) {
    __shared__ int s[512];
    int t = threadIdx.x;
    int v = (t < nb) ? bsum[t] : 0;
    s[t] = v;
    __syncthreads();
    for (int st = 1; st < 512; st <<= 1) {
        int x = (t >= st) ? s[t - st] : 0;
        __syncthreads();
        s[t] += x;
        __syncthreads();
    }
    if (t < nb) bbase[t] = s[t] - v;   // exclusive
}

__global__ void k_scan3(const int* __restrict__ deg, int N,
                        const int* __restrict__ bbase,
                        int* __restrict__ off, int* __restrict__ cursor) {
    __shared__ int s[SCB];
    int t = threadIdx.x, i = blockIdx.x * SCB + t;
    int v = (i < N) ? deg[i] : 0;
    s[t] = v;
    __syncthreads();
    for (int st = 1; st < SCB; st <<= 1) {
        int x = (t >= st) ? s[t - st] : 0;
        __syncthreads();
        s[t] += x;
        __syncthreads();
    }
    if (i < N) {
        int o = bbase[blockIdx.x] + s[t] - v;
        off[i] = o;
        cursor[i] = o;
    }
}

// fill: scatter per-edge data into dst-sorted position
__global__ void k_fill2(const int* __restrict__ ei,
                        const float* __restrict__ lu, const float* __restrict__ tt,
                        const float* __restrict__ msg, int E,
                        int* __restrict__ cursor,
                        int* __restrict__ esrcs, int* __restrict__ edst,
                        float2* __restrict__ aux_rm) {
    int e = blockIdx.x * blockDim.x + threadIdx.x;
    if (e >= E) return;
    int sn = ei[e], dn = ei[E + e];
    int pos = atomicAdd(&cursor[dn], 1);
    esrcs[pos] = sn;
    edst[pos] = dn;
    aux_rm[pos] = make_float2(lu[sn] - tt[e], msg[e]);
}

// ---------------- K1: MFMA fused node GEMM ----------------
// 64 nodes x 80 cols per block (8 y-tiles); A hi/lo split (2 MFMA), B hi only.
// LDS stride 136 halfs -> max 2-way bank conflict (free). B tile = 20KB -> L1-hot.
__global__ __launch_bounds__(256) void k_gemm(
    const float* __restrict__ z,
    const __half* __restrict__ WTh,
    const float* __restrict__ bias_all,
    __half* __restrict__ qh, __half* __restrict__ kh, __half* __restrict__ vh,
    float* __restrict__ zbuf, __half* __restrict__ qW0h, __half* __restrict__ qW1h,
    int N)
{
    __shared__ __half zsh[64][LDSK];
    __shared__ __half zsl[64][LDSK];
    int tid = threadIdx.x;
    int m0 = blockIdx.x * 64;
    int cols0 = blockIdx.y * 80;

    for (int idx = tid; idx < 64 * 25; idx += 256) {
        int row = idx / 25, c4 = idx % 25;
        int node = m0 + row;
        float4 zz = (node < N) ? ((const float4*)(z + (size_t)node * TDIM))[c4]
                               : make_float4(0.f, 0.f, 0.f, 0.f);
        __half2 h01 = __floats2half2_rn(zz.x, zz.y);
        __half2 h23 = __floats2half2_rn(zz.z, zz.w);
        float2 f01 = __half22float2(h01);
        float2 f23 = __half22float2(h23);
        *(__half2*)&zsh[row][c4 * 4]     = h01;
        *(__half2*)&zsh[row][c4 * 4 + 2] = h23;
        *(__half2*)&zsl[row][c4 * 4]     = __floats2half2_rn(zz.x - f01.x, zz.y - f01.y);
        *(__half2*)&zsl[row][c4 * 4 + 2] = __floats2half2_rn(zz.z - f23.x, zz.w - f23.y);
    }
    for (int idx = tid; idx < 64 * 28; idx += 256) {
        int row = idx / 28, k = TDIM + idx % 28;
        zsh[row][k] = __half(0.f);
        zsl[row][k] = __half(0.f);
    }
    __syncthreads();

    int wave = tid >> 6, lane = tid & 63;
    int arow = wave * 16 + (lane & 15);
    int kgrp = (lane >> 4) * 8;
    f32x4 acc[5];
#pragma unroll
    for (int c = 0; c < 5; ++c) acc[c] = f32x4{0.f, 0.f, 0.f, 0.f};

#pragma unroll
    for (int kk = 0; kk < KPAD; kk += 32) {
        f16x8 ah = *(const f16x8*)&zsh[arow][kk + kgrp];
        f16x8 al = *(const f16x8*)&zsl[arow][kk + kgrp];
#pragma unroll
        for (int c = 0; c < 5; ++c) {
            int col = cols0 + c * 16 + (lane & 15);
            f16x8 bh = *(const f16x8*)&WTh[col * KPAD + kk + kgrp];
            acc[c] = __builtin_amdgcn_mfma_f32_16x16x32_f16(ah, bh, acc[c], 0, 0, 0);
            acc[c] = __builtin_amdgcn_mfma_f32_16x16x32_f16(al, bh, acc[c], 0, 0, 0);
        }
    }

#pragma unroll
    for (int c = 0; c < 5; ++c) {
        int col = cols0 + c * 16 + (lane & 15);
        if (col >= 602) continue;
        float bias = bias_all[col];
#pragma unroll
        for (int r = 0; r < 4; ++r) {
            int node = m0 + wave * 16 + (lane >> 4) * 4 + r;
            if (node >= N) continue;
            float val = acc[c][r] + bias;
            if (col < 100)      qh[(size_t)node * TDIM + col]          = __float2half(val);
            else if (col < 200) kh[(size_t)node * TDIM + col - 100]    = __float2half(val);
            else if (col < 300) vh[(size_t)node * TDIM + col - 200]    = __float2half(val);
            else if (col < 400) zbuf[(size_t)node * TDIM + col - 300]  = val;
            else if (col < 501) qW0h[(size_t)node * EDGEP + col - 400] = __float2half(val);
            else                qW1h[(size_t)node * EDGEP + col - 501] = __float2half(val);
        }
    }
}

// ---------------- K2a: edge-parallel logits (dst-sorted order) ----------------
__global__ __launch_bounds__(256) void k_logit2(
    const float2* __restrict__ aux_rm,
    const int* __restrict__ esrcs, const int* __restrict__ edst,
    const float* __restrict__ tw, const float* __restrict__ tb,
    const __half* __restrict__ qh, const __half* __restrict__ kh,
    const __half* __restrict__ qW0h, const __half* __restrict__ qW1h,
    int E, float4* __restrict__ aux_s)
{
    const float INVS = 0.14142135623730951f;   // 1/sqrt(50)
    int p = blockIdx.x * 256 + threadIdx.x;
    if (p >= E) return;
    float2 rm = aux_rm[p];
    int sn = esrcs[p], dn = edst[p];
    float rel = rm.x, m = rm.y;

    const __half2* q2 = (const __half2*)(qh + (size_t)dn * TDIM);
    const __half2* k2 = (const __half2*)(kh + (size_t)sn * TDIM);
    float qk0 = 0.f, qk1 = 0.f;
#pragma unroll
    for (int c = 0; c < 25; ++c) {
        float2 qq = __half22float2(q2[c]);
        float2 kk = __half22float2(k2[c]);
        qk0 = fmaf(qq.x, kk.x, qk0);
        qk0 = fmaf(qq.y, kk.y, qk0);
    }
#pragma unroll
    for (int c = 25; c < 50; ++c) {
        float2 qq = __half22float2(q2[c]);
        float2 kk = __half22float2(k2[c]);
        qk1 = fmaf(qq.x, kk.x, qk1);
        qk1 = fmaf(qq.y, kk.y, qk1);
    }

    const __half2* w02 = (const __half2*)(qW0h + (size_t)dn * EDGEP);
    const __half2* w12 = (const __half2*)(qW1h + (size_t)dn * EDGEP);
    float l0 = qk0, l1 = qk1;
#pragma unroll 5
    for (int c = 0; c < 50; ++c) {
        float cv0 = __cosf(fmaf(rel, tw[2 * c], tb[2 * c]));
        float cv1 = __cosf(fmaf(rel, tw[2 * c + 1], tb[2 * c + 1]));
        float2 w0 = __half22float2(w02[c]);
        float2 w1 = __half22float2(w12[c]);
        l0 = fmaf(w0.x, cv0, l0); l0 = fmaf(w0.y, cv1, l0);
        l1 = fmaf(w1.x, cv0, l1); l1 = fmaf(w1.y, cv1, l1);
    }
    l0 = fmaf(__half2float(qW0h[(size_t)dn * EDGEP + 100]), m, l0);
    l1 = fmaf(__half2float(qW1h[(size_t)dn * EDGEP + 100]), m, l1);

    aux_s[p] = make_float4(rel, m, __expf(l0 * INVS), __expf(l1 * INVS));
}

// ---------------- K2b: 6-waves-per-node segment sums ----------------
__global__ __launch_bounds__(256) void k_gather3(
    const float* __restrict__ tw, const float* __restrict__ tb,
    const __half* __restrict__ vh, const int* __restrict__ esrcs,
    const float4* __restrict__ aux_s,
    const int* __restrict__ off, const int* __restrict__ deg,
    int N, float* __restrict__ zbuf, float* __restrict__ CW)
{
    int gw = (blockIdx.x * 256 + threadIdx.x) >> 6;
    int lane = threadIdx.x & 63;
    int n = gw / 6;
    int role = gw - n * 6;
    if (n >= N) return;
    int dg = deg[n], nb = off[n];

    if (role < 2) {
        int d = role * 64 + lane;
        bool act = d < TDIM;
        bool h1 = d >= HALFC;
        float acc = 0.f, den = 0.f;
        for (int i = 0; i < dg; ++i) {
            float4 ax = aux_s[nb + i];            // wave-uniform broadcast
            int sn = esrcs[nb + i];               // wave-uniform
            float a = h1 ? ax.w : ax.z;
            den += a;
            if (act) acc = fmaf(a, __half2float(vh[(size_t)sn * TDIM + d]), acc);
        }
        if (dg > 0 && act) zbuf[(size_t)n * TDIM + d] += acc / den;
    } else {
        int r2 = role - 2;
        int hh = r2 >> 1, sub = r2 & 1;
        int j = sub * 64 + lane;
        bool act = j < EDGED;
        float twj = (j < TDIM) ? tw[j] : 0.f;
        float tbj = (j < TDIM) ? tb[j] : 0.f;
        float acc = 0.f, den = 0.f;
        for (int i = 0; i < dg; ++i) {
            float4 ax = aux_s[nb + i];
            float a = hh ? ax.w : ax.z;
            den += a;
            float cv = (j < TDIM) ? __cosf(fmaf(ax.x, twj, tbj)) : ax.y;
            acc = fmaf(a, cv, acc);
        }
        if (act) CW[(size_t)n * CWS + hh * EDGED + j] = (dg > 0) ? acc / den : 0.f;
    }
}

// ---------------- K3: MFMA CW GEMM: zbuf += CW[N x 202] * We2 ----------------
__global__ __launch_bounds__(256) void k_gemmCW(
    const float* __restrict__ CW,
    const __half* __restrict__ WT2h,
    int N, float* __restrict__ zbuf)
{
    __shared__ __half ash[64][K2L];
    __shared__ __half asl[64][K2L];
    int tid = threadIdx.x;
    int m0 = blockIdx.x * 64;

    for (int idx = tid; idx < 64 * K2P; idx += 256) {
        int row = idx / K2P, k = idx - (idx / K2P) * K2P;
        int node = m0 + row;
        float vv = (k < 2 * EDGED && node < N) ? CW[(size_t)node * CWS + k] : 0.f;
        __half h = __float2half(vv);
        ash[row][k] = h;
        asl[row][k] = __float2half(vv - __half2float(h));
    }
    __syncthreads();

    int wave = tid >> 6, lane = tid & 63;
    int arow = wave * 16 + (lane & 15);
    int kgrp = (lane >> 4) * 8;
    f32x4 acc[7];
#pragma unroll
    for (int c = 0; c < 7; ++c) acc[c] = f32x4{0.f, 0.f, 0.f, 0.f};

#pragma unroll
    for (int kk = 0; kk < K2P; kk += 32) {
        f16x8 ah = *(const f16x8*)&ash[arow][kk + kgrp];
        f16x8 al = *(const f16x8*)&asl[arow][kk + kgrp];
#pragma unroll
        for (int c = 0; c < 7; ++c) {
            int col = c * 16 + (lane & 15);
            f16x8 bh = *(const f16x8*)&WT2h[col * K2P + kk + kgrp];
            acc[c] = __builtin_amdgcn_mfma_f32_16x16x32_f16(ah, bh, acc[c], 0, 0, 0);
            acc[c] = __builtin_amdgcn_mfma_f32_16x16x32_f16(al, bh, acc[c], 0, 0, 0);
        }
    }

#pragma unroll
    for (int c = 0; c < 7; ++c) {
        int col = c * 16 + (lane & 15);
        if (col >= TDIM) continue;
#pragma unroll
        for (int r = 0; r < 4; ++r) {
            int node = m0 + wave * 16 + (lane >> 4) * 4 + r;
            if (node >= N) continue;
            size_t o = (size_t)node * TDIM + col;
            zbuf[o] += acc[c][r];
        }
    }
}

// ---------------- K4: link predictor ----------------
#define LPB 64
__global__ __launch_bounds__(256) void k_link(
    const float* __restrict__ zout,
    const float* __restrict__ Wsr, const float* __restrict__ bsr,
    const float* __restrict__ Wds, const float* __restrict__ bds,
    const float* __restrict__ Wf, const float* __restrict__ bf,
    const int* __restrict__ assoc, const int* __restrict__ src,
    const int* __restrict__ dst, int B, float* __restrict__ outp)
{
    __shared__ float zs[LPB][EDGED];
    __shared__ float zd[LPB][EDGED];
    __shared__ int rowS[LPB], rowD[LPB];
    int tid = threadIdx.x;
    int l0 = blockIdx.x * LPB;
    if (tid < LPB) {
        int li = l0 + tid;
        rowS[tid] = (li < B) ? assoc[src[li]] : 0;
        rowD[tid] = (li < B) ? assoc[dst[li]] : 0;
    }
    __syncthreads();
    for (int i = tid; i < LPB * TDIM; i += 256) {
        int l = i / TDIM, d2 = i - l * TDIM;
        zs[l][d2] = zout[(size_t)rowS[l] * TDIM + d2];
        zd[l][d2] = zout[(size_t)rowD[l] * TDIM + d2];
    }
    __syncthreads();
    int l = tid >> 2, qt = tid & 3;
    float part = 0.f;
    for (int oo = 0; oo < 25; ++oo) {
        int out = qt * 25 + oo;
        const float4* ws4 = (const float4*)(Wsr + out * TDIM);
        const float4* wd4 = (const float4*)(Wds + out * TDIM);
        float accS = 0.f, accD = 0.f;
#pragma unroll
        for (int j = 0; j < 25; ++j) {
            float4 a = ws4[j];
            float4 b = wd4[j];
            accS = fmaf(a.x, zs[l][4*j+0], accS); accS = fmaf(a.y, zs[l][4*j+1], accS);
            accS = fmaf(a.z, zs[l][4*j+2], accS); accS = fmaf(a.w, zs[l][4*j+3], accS);
            accD = fmaf(b.x, zd[l][4*j+0], accD); accD = fmaf(b.y, zd[l][4*j+1], accD);
            accD = fmaf(b.z, zd[l][4*j+2], accD); accD = fmaf(b.w, zd[l][4*j+3], accD);
        }
        float h = accS + accD + bsr[out] + bds[out];
        h = fmaxf(h, 0.f);
        part = fmaf(Wf[out], h, part);
    }
    part += __shfl_xor(part, 1);
    part += __shfl_xor(part, 2);
    int li = l0 + l;
    if (qt == 0 && li < B) outp[li] = part + bf[0];
}

extern "C" void kernel_launch(void* const* d_in, const int* in_sizes, int n_in,
                              void* d_out, int out_size, void* d_ws, size_t ws_size,
                              hipStream_t stream)
{
    const float* z   = (const float*)d_in[0];
    const float* lu  = (const float*)d_in[1];
    const float* tt  = (const float*)d_in[2];
    const float* msg = (const float*)d_in[3];
    const float* tw  = (const float*)d_in[4];
    const float* tb  = (const float*)d_in[5];
    const float* Wq  = (const float*)d_in[6];  const float* bq  = (const float*)d_in[7];
    const float* Wk  = (const float*)d_in[8];  const float* bk  = (const float*)d_in[9];
    const float* Wv  = (const float*)d_in[10]; const float* bv  = (const float*)d_in[11];
    const float* We  = (const float*)d_in[12];
    const float* Wsk = (const float*)d_in[13]; const float* bsk = (const float*)d_in[14];
    const float* Wsr = (const float*)d_in[15]; const float* bsr = (const float*)d_in[16];
    const float* Wds = (const float*)d_in[17]; const float* bds = (const float*)d_in[18];
    const float* Wf  = (const float*)d_in[19]; const float* bf  = (const float*)d_in[20];
    const int* n_id  = (const int*)d_in[21];
    const int* srcI  = (const int*)d_in[22];
    const int* dstI  = (const int*)d_in[23];
    const int* ei    = (const int*)d_in[24];

    int N = in_sizes[0] / TDIM;   // 100000
    int E = in_sizes[2];          // 500000
    int B = in_sizes[22];         // 20000
    const size_t NUM_NODES = 1000000;
    int nblk = (N + SCB - 1) / SCB;

    char* w = (char*)d_ws;
    int*    assoc = (int*)w;    w += NUM_NODES * sizeof(int);          // 4.0 MB
    float2* auxrm = (float2*)w; w += (size_t)E * 8;                    // 4.0 MB
    float4* aux_s = (float4*)w; w += (size_t)E * 16;                   // 8.0 MB
    int*    esrcs = (int*)w;    w += (size_t)E * 4;                    // 2.0 MB
    int*    edst  = (int*)w;    w += (size_t)E * 4;                    // 2.0 MB
    __half* vh    = (__half*)w; w += (size_t)N * TDIM * 2;             // 20 MB
    float*  zbuf  = (float*)w;  w += (size_t)N * TDIM * 4;             // 40 MB
    // UNION: q/k/qW (GEMM+logit phase) aliased with CW (gather+gemmCW phase)
    char*   uni   = w;
    __half* qh    = (__half*)uni;
    __half* kh    = (__half*)(uni + (size_t)N * TDIM * 2);
    __half* qW0h  = (__half*)(uni + (size_t)N * TDIM * 4);
    __half* qW1h  = (__half*)(uni + (size_t)N * TDIM * 4 + (size_t)N * EDGEP * 2);
    float*  CW    = (float*)uni;                                       // N*204*4 = 81.6 MB
    w += (size_t)N * CWS * 4;                                          // 81.6 MB
    __half* WTh   = (__half*)w; w += (size_t)NCOLP * KPAD * 2;         // 160 KB
    __half* WTl   = (__half*)w; w += (size_t)NCOLP * KPAD * 2;         // 160 KB (unused, kept for layout)
    __half* WT2h  = (__half*)w; w += (size_t)NCOL2 * K2P * 2;          // 50 KB
    float*  biasA = (float*)w;  w += NCOLP * 4;
    int*    deg   = (int*)w;    w += (size_t)N * sizeof(int);
    int*    off   = (int*)w;    w += (size_t)N * sizeof(int);
    int*    curs  = (int*)w;    w += (size_t)N * sizeof(int);
    int*    bsum  = (int*)w;    w += 512 * sizeof(int);
    int*    bbase = (int*)w;    w += 512 * sizeof(int);
    // total ~163 MB

    hipLaunchKernelGGL(k_prep, dim3((N + 255) / 256), dim3(256), 0, stream,
                       n_id, N, assoc, deg);
    hipLaunchKernelGGL(k_precomp2,
                       dim3((NCOLP * KPAD + NCOL2 * K2P + NCOLP + 255) / 256), dim3(256), 0, stream,
                       Wq, bq, Wk, bk, Wv, bv, Wsk, bsk, We, WTh, WTl, WT2h, biasA);
    hipLaunchKernelGGL(k_count, dim3((E + 255) / 256), dim3(256), 0, stream, ei, E, deg);
    hipLaunchKernelGGL(k_scan1, dim3(nblk), dim3(SCB), 0, stream, deg, N, bsum);
    hipLaunchKernelGGL(k_scan2, dim3(1), dim3(512), 0, stream, bsum, nblk, bbase);
    hipLaunchKernelGGL(k_scan3, dim3(nblk), dim3(SCB), 0, stream, deg, N, bbase, off, curs);
    hipLaunchKernelGGL(k_fill2, dim3((E + 255) / 256), dim3(256), 0, stream,
                       ei, lu, tt, msg, E, curs, esrcs, edst, auxrm);
    hipLaunchKernelGGL(k_gemm, dim3((N + 63) / 64, 8), dim3(256), 0, stream,
                       z, WTh, biasA, qh, kh, vh, zbuf, qW0h, qW1h, N);
    hipLaunchKernelGGL(k_logit2, dim3((E + 255) / 256), dim3(256), 0, stream,
                       auxrm, esrcs, edst, tw, tb, qh, kh, qW0h, qW1h, E, aux_s);
    hipLaunchKernelGGL(k_gather3, dim3(((size_t)N * 6 + 3) / 4), dim3(256), 0, stream,
                       tw, tb, vh, esrcs, aux_s, off, deg, N, zbuf, CW);
    hipLaunchKernelGGL(k_gemmCW, dim3((N + 63) / 64), dim3(256), 0, stream,
                       CW, WT2h, N, zbuf);
    hipLaunchKernelGGL(k_link, dim3((B + LPB - 1) / LPB), dim3(256), 0, stream,
                       zbuf, Wsr, bsr, Wds, bds, Wf, bf, assoc, srcI, dstI, B,
                       (float*)d_out);
}

// Round 8
// 898.627 us; speedup vs baseline: 1.6309x; 1.2440x over previous
//
#include <hip/hip_runtime.h>
#include <hip/hip_fp16.h>
#include <math.h>

#define TDIM 100      // D
#define EDGED 101     // D + MSG_DIM
#define EDGEP 104     // padded qW row stride (halfs)
#define HALFC 50      // per-head channels
#define NCOLP 640     // padded fused-output columns (602 real)
#define KPAD 128      // padded K for node GEMM (global WT stride)
#define LDSK 136      // LDS row stride for node GEMM (272B = 17*16B -> 2-way max)
#define NCOL2 112     // padded out cols for CW GEMM (100 real)
#define K2P 224       // padded K for CW GEMM (202 real, global WT2 stride)
#define K2L 232       // LDS row stride for CW GEMM (464B = 29*16B)
#define CWS2 208      // CW row stride (halfs)
#define SCB 256

typedef __attribute__((ext_vector_type(8))) _Float16 f16x8;
typedef __attribute__((ext_vector_type(4))) float f32x4;

// ---------------- K0: assoc + deg zero ----------------
__global__ void k_prep(const int* __restrict__ n_id, int N,
                       int* __restrict__ assoc, int* __restrict__ deg) {
    int i = blockIdx.x * blockDim.x + threadIdx.x;
    if (i < N) {
        assoc[n_id[i]] = i;
        deg[i] = 0;
    }
}

// ---------------- K0a: fused weights (WT for node GEMM, WT2 for CW GEMM) ------
__global__ __launch_bounds__(256) void k_precomp2(
    const float* __restrict__ Wq, const float* __restrict__ bq,
    const float* __restrict__ Wk, const float* __restrict__ bk,
    const float* __restrict__ Wv, const float* __restrict__ bv,
    const float* __restrict__ Ws, const float* __restrict__ bs,
    const float* __restrict__ We,
    __half* __restrict__ WTh, __half* __restrict__ WTl,
    __half* __restrict__ WT2h,
    float* __restrict__ bias_all)
{
    int t = blockIdx.x * blockDim.x + threadIdx.x;
    if (t < NCOLP * KPAD) {
        int col = t >> 7, k = t & 127;
        float val = 0.f;
        if (k < TDIM && col < 602) {
            if (col < 100)      val = Wq[col * TDIM + k];
            else if (col < 200) val = Wk[(col - 100) * TDIM + k];
            else if (col < 300) val = Wv[(col - 200) * TDIM + k];
            else if (col < 400) val = Ws[(col - 300) * TDIM + k];
            else if (col < 501) {
                int j = col - 400;
                for (int d = 0; d < HALFC; ++d)
                    val = fmaf(Wq[d * TDIM + k], We[d * EDGED + j], val);
            } else {
                int j = col - 501;
                for (int d = HALFC; d < TDIM; ++d)
                    val = fmaf(Wq[d * TDIM + k], We[d * EDGED + j], val);
            }
        }
        __half h = __float2half(val);
        WTh[t] = h;
        WTl[t] = __float2half(val - __half2float(h));
        return;
    }
    int t2 = t - NCOLP * KPAD;
    if (t2 < NCOL2 * K2P) {
        int col = t2 / K2P, k = t2 - (t2 / K2P) * K2P;
        float val = 0.f;
        if (col < TDIM) {
            if (k < EDGED && col < HALFC)                      // head0 block
                val = We[col * EDGED + k];
            else if (k >= EDGED && k < 2 * EDGED && col >= HALFC)  // head1 block
                val = We[col * EDGED + (k - EDGED)];
        }
        WT2h[t2] = __float2half(val);
        return;
    }
    int i = t2 - NCOL2 * K2P;
    if (i < NCOLP) {
        float b = 0.f;
        if (i < 100)      b = bq[i];
        else if (i < 200) b = bk[i - 100];
        else if (i < 300) b = bv[i - 200];
        else if (i < 400) b = bs[i - 300];
        else if (i < 501) {
            int j = i - 400;
            for (int d = 0; d < HALFC; ++d) b = fmaf(bq[d], We[d * EDGED + j], b);
        } else if (i < 602) {
            int j = i - 501;
            for (int d = HALFC; d < TDIM; ++d) b = fmaf(bq[d], We[d * EDGED + j], b);
        }
        bias_all[i] = b;
    }
}

// ---------------- CSR build ----------------
__global__ void k_count(const int* __restrict__ ei, int E, int* __restrict__ deg) {
    int e = blockIdx.x * blockDim.x + threadIdx.x;
    if (e < E) atomicAdd(&deg[ei[E + e]], 1);
}

__global__ void k_scan1(const int* __restrict__ deg, int N, int* __restrict__ bsum) {
    __shared__ int s[SCB];
    int t = threadIdx.x, i = blockIdx.x * SCB + t;
    s[t] = (i < N) ? deg[i] : 0;
    __syncthreads();
    for (int st = SCB / 2; st > 0; st >>= 1) {
        if (t < st) s[t] += s[t + st];
        __syncthreads();
    }
    if (t == 0) bsum[blockIdx.x] = s[0];
}

__global__ void k_scan2(const int* __restrict__ bsum, int nb, int* __restrict__ bbase) {
    __shared__ int s[512];
    int t = threadIdx.x;
    int v = (t < nb) ? bsum[t] : 0;
    s[t] = v;
    __syncthreads();
    for (int st = 1; st < 512; st <<= 1) {
        int x = (t >= st) ? s[t - st] : 0;
        __syncthreads();
        s[t] += x;
        __syncthreads();
    }
    if (t < nb) bbase[t] = s[t] - v;   // exclusive
}

__global__ void k_scan3(const int* __restrict__ deg, int N,
                        const int* __restrict__ bbase,
                        int* __restrict__ off, int* __restrict__ cursor) {
    __shared__ int s[SCB];
    int t = threadIdx.x, i = blockIdx.x * SCB + t;
    int v = (i < N) ? deg[i] : 0;
    s[t] = v;
    __syncthreads();
    for (int st = 1; st < SCB; st <<= 1) {
        int x = (t >= st) ? s[t - st] : 0;
        __syncthreads();
        s[t] += x;
        __syncthreads();
    }
    if (i < N) {
        int o = bbase[blockIdx.x] + s[t] - v;
        off[i] = o;
        cursor[i] = o;
    }
}

// fill: scatter per-edge data into dst-sorted position
__global__ void k_fill2(const int* __restrict__ ei,
                        const float* __restrict__ lu, const float* __restrict__ tt,
                        const float* __restrict__ msg, int E,
                        int* __restrict__ cursor,
                        int* __restrict__ esrcs, int* __restrict__ edst,
                        float2* __restrict__ aux_rm) {
    int e = blockIdx.x * blockDim.x + threadIdx.x;
    if (e >= E) return;
    int sn = ei[e], dn = ei[E + e];
    int pos = atomicAdd(&cursor[dn], 1);
    esrcs[pos] = sn;
    edst[pos] = dn;
    aux_rm[pos] = make_float2(lu[sn] - tt[e], msg[e]);
}

// ---------------- K1: MFMA fused node GEMM ----------------
__global__ __launch_bounds__(256) void k_gemm(
    const float* __restrict__ z,
    const __half* __restrict__ WTh,
    const float* __restrict__ bias_all,
    __half* __restrict__ qh, __half* __restrict__ kh, __half* __restrict__ vh,
    float* __restrict__ zbuf, __half* __restrict__ qW0h, __half* __restrict__ qW1h,
    int N)
{
    __shared__ __half zsh[64][LDSK];
    __shared__ __half zsl[64][LDSK];
    int tid = threadIdx.x;
    int m0 = blockIdx.x * 64;
    int cols0 = blockIdx.y * 80;

    for (int idx = tid; idx < 64 * 25; idx += 256) {
        int row = idx / 25, c4 = idx % 25;
        int node = m0 + row;
        float4 zz = (node < N) ? ((const float4*)(z + (size_t)node * TDIM))[c4]
                               : make_float4(0.f, 0.f, 0.f, 0.f);
        __half2 h01 = __floats2half2_rn(zz.x, zz.y);
        __half2 h23 = __floats2half2_rn(zz.z, zz.w);
        float2 f01 = __half22float2(h01);
        float2 f23 = __half22float2(h23);
        *(__half2*)&zsh[row][c4 * 4]     = h01;
        *(__half2*)&zsh[row][c4 * 4 + 2] = h23;
        *(__half2*)&zsl[row][c4 * 4]     = __floats2half2_rn(zz.x - f01.x, zz.y - f01.y);
        *(__half2*)&zsl[row][c4 * 4 + 2] = __floats2half2_rn(zz.z - f23.x, zz.w - f23.y);
    }
    for (int idx = tid; idx < 64 * 28; idx += 256) {
        int row = idx / 28, k = TDIM + idx % 28;
        zsh[row][k] = __half(0.f);
        zsl[row][k] = __half(0.f);
    }
    __syncthreads();

    int wave = tid >> 6, lane = tid & 63;
    int arow = wave * 16 + (lane & 15);
    int kgrp = (lane >> 4) * 8;
    f32x4 acc[5];
#pragma unroll
    for (int c = 0; c < 5; ++c) acc[c] = f32x4{0.f, 0.f, 0.f, 0.f};

#pragma unroll
    for (int kk = 0; kk < KPAD; kk += 32) {
        f16x8 ah = *(const f16x8*)&zsh[arow][kk + kgrp];
        f16x8 al = *(const f16x8*)&zsl[arow][kk + kgrp];
#pragma unroll
        for (int c = 0; c < 5; ++c) {
            int col = cols0 + c * 16 + (lane & 15);
            f16x8 bh = *(const f16x8*)&WTh[col * KPAD + kk + kgrp];
            acc[c] = __builtin_amdgcn_mfma_f32_16x16x32_f16(ah, bh, acc[c], 0, 0, 0);
            acc[c] = __builtin_amdgcn_mfma_f32_16x16x32_f16(al, bh, acc[c], 0, 0, 0);
        }
    }

#pragma unroll
    for (int c = 0; c < 5; ++c) {
        int col = cols0 + c * 16 + (lane & 15);
        if (col >= 602) continue;
        float bias = bias_all[col];
#pragma unroll
        for (int r = 0; r < 4; ++r) {
            int node = m0 + wave * 16 + (lane >> 4) * 4 + r;
            if (node >= N) continue;
            float val = acc[c][r] + bias;
            if (col < 100)      qh[(size_t)node * TDIM + col]          = __float2half(val);
            else if (col < 200) kh[(size_t)node * TDIM + col - 100]    = __float2half(val);
            else if (col < 300) vh[(size_t)node * TDIM + col - 200]    = __float2half(val);
            else if (col < 400) zbuf[(size_t)node * TDIM + col - 300]  = val;
            else if (col < 501) qW0h[(size_t)node * EDGEP + col - 400] = __float2half(val);
            else                qW1h[(size_t)node * EDGEP + col - 501] = __float2half(val);
        }
    }
}

// ---------------- K2a: edge-parallel logits (dst-sorted order) ----------------
__global__ __launch_bounds__(256) void k_logit2(
    const float2* __restrict__ aux_rm,
    const int* __restrict__ esrcs, const int* __restrict__ edst,
    const float* __restrict__ tw, const float* __restrict__ tb,
    const __half* __restrict__ qh, const __half* __restrict__ kh,
    const __half* __restrict__ qW0h, const __half* __restrict__ qW1h,
    int E, float4* __restrict__ aux_s)
{
    const float INVS = 0.14142135623730951f;   // 1/sqrt(50)
    int p = blockIdx.x * 256 + threadIdx.x;
    if (p >= E) return;
    float2 rm = aux_rm[p];
    int sn = esrcs[p], dn = edst[p];
    float rel = rm.x, m = rm.y;

    const __half2* q2 = (const __half2*)(qh + (size_t)dn * TDIM);
    const __half2* k2 = (const __half2*)(kh + (size_t)sn * TDIM);
    float qk0 = 0.f, qk1 = 0.f;
#pragma unroll
    for (int c = 0; c < 25; ++c) {
        float2 qq = __half22float2(q2[c]);
        float2 kk = __half22float2(k2[c]);
        qk0 = fmaf(qq.x, kk.x, qk0);
        qk0 = fmaf(qq.y, kk.y, qk0);
    }
#pragma unroll
    for (int c = 25; c < 50; ++c) {
        float2 qq = __half22float2(q2[c]);
        float2 kk = __half22float2(k2[c]);
        qk1 = fmaf(qq.x, kk.x, qk1);
        qk1 = fmaf(qq.y, kk.y, qk1);
    }

    const __half2* w02 = (const __half2*)(qW0h + (size_t)dn * EDGEP);
    const __half2* w12 = (const __half2*)(qW1h + (size_t)dn * EDGEP);
    float l0 = qk0, l1 = qk1;
#pragma unroll 5
    for (int c = 0; c < 50; ++c) {
        float cv0 = __cosf(fmaf(rel, tw[2 * c], tb[2 * c]));
        float cv1 = __cosf(fmaf(rel, tw[2 * c + 1], tb[2 * c + 1]));
        float2 w0 = __half22float2(w02[c]);
        float2 w1 = __half22float2(w12[c]);
        l0 = fmaf(w0.x, cv0, l0); l0 = fmaf(w0.y, cv1, l0);
        l1 = fmaf(w1.x, cv0, l1); l1 = fmaf(w1.y, cv1, l1);
    }
    l0 = fmaf(__half2float(qW0h[(size_t)dn * EDGEP + 100]), m, l0);
    l1 = fmaf(__half2float(qW1h[(size_t)dn * EDGEP + 100]), m, l1);

    aux_s[p] = make_float4(rel, m, __expf(l0 * INVS), __expf(l1 * INVS));
}

// ---------------- K2b: block-per-node segment sums, 4 roles, 4x unrolled ------
// role 0/1: vsum over d-range; role 2/3: cw for BOTH heads over j-range
// (cos computed once, feeds 2 FMAs). Batched loads break the serial
// load->use chain (round-7 k_gather3 was VGPR=8 fully-serial).
__global__ __launch_bounds__(256) void k_gather4(
    const float* __restrict__ tw, const float* __restrict__ tb,
    const __half* __restrict__ vh, const int* __restrict__ esrcs,
    const float4* __restrict__ aux_s,
    const int* __restrict__ off, const int* __restrict__ deg,
    int N, float* __restrict__ zbuf, __half* __restrict__ CWh)
{
    int n = blockIdx.x;
    int role = threadIdx.x >> 6;
    int lane = threadIdx.x & 63;
    int dg = deg[n], nb = off[n];

    if (role < 2) {
        int d = role * 64 + lane;
        bool act = d < TDIM;
        bool h1 = d >= HALFC;
        float acc = 0.f, den = 0.f;
        const float4* ap = aux_s + nb;
        const int* sp = esrcs + nb;
        int i = 0;
        for (; i + 4 <= dg; i += 4) {
            float4 ax0 = ap[i], ax1 = ap[i + 1], ax2 = ap[i + 2], ax3 = ap[i + 3];
            int s0 = sp[i], s1 = sp[i + 1], s2 = sp[i + 2], s3 = sp[i + 3];
            float v0 = act ? __half2float(vh[(size_t)s0 * TDIM + d]) : 0.f;
            float v1 = act ? __half2float(vh[(size_t)s1 * TDIM + d]) : 0.f;
            float v2 = act ? __half2float(vh[(size_t)s2 * TDIM + d]) : 0.f;
            float v3 = act ? __half2float(vh[(size_t)s3 * TDIM + d]) : 0.f;
            float a0 = h1 ? ax0.w : ax0.z;
            float a1 = h1 ? ax1.w : ax1.z;
            float a2 = h1 ? ax2.w : ax2.z;
            float a3 = h1 ? ax3.w : ax3.z;
            den += (a0 + a1) + (a2 + a3);
            acc = fmaf(a0, v0, acc); acc = fmaf(a1, v1, acc);
            acc = fmaf(a2, v2, acc); acc = fmaf(a3, v3, acc);
        }
        for (; i < dg; ++i) {
            float4 ax = ap[i];
            int s = sp[i];
            float a = h1 ? ax.w : ax.z;
            den += a;
            if (act) acc = fmaf(a, __half2float(vh[(size_t)s * TDIM + d]), acc);
        }
        if (dg > 0 && act) zbuf[(size_t)n * TDIM + d] += acc / den;
    } else {
        int j = (role - 2) * 64 + lane;
        bool act = j < EDGED;
        bool isMsg = (j == TDIM);
        float twj = (j < TDIM) ? tw[j] : 0.f;
        float tbj = (j < TDIM) ? tb[j] : 0.f;
        float acc0 = 0.f, acc1 = 0.f, den0 = 0.f, den1 = 0.f;
        const float4* ap = aux_s + nb;
        int i = 0;
        for (; i + 4 <= dg; i += 4) {
            float4 ax0 = ap[i], ax1 = ap[i + 1], ax2 = ap[i + 2], ax3 = ap[i + 3];
            float cv0 = isMsg ? ax0.y : __cosf(fmaf(ax0.x, twj, tbj));
            float cv1 = isMsg ? ax1.y : __cosf(fmaf(ax1.x, twj, tbj));
            float cv2 = isMsg ? ax2.y : __cosf(fmaf(ax2.x, twj, tbj));
            float cv3 = isMsg ? ax3.y : __cosf(fmaf(ax3.x, twj, tbj));
            den0 += (ax0.z + ax1.z) + (ax2.z + ax3.z);
            den1 += (ax0.w + ax1.w) + (ax2.w + ax3.w);
            acc0 = fmaf(ax0.z, cv0, acc0); acc0 = fmaf(ax1.z, cv1, acc0);
            acc0 = fmaf(ax2.z, cv2, acc0); acc0 = fmaf(ax3.z, cv3, acc0);
            acc1 = fmaf(ax0.w, cv0, acc1); acc1 = fmaf(ax1.w, cv1, acc1);
            acc1 = fmaf(ax2.w, cv2, acc1); acc1 = fmaf(ax3.w, cv3, acc1);
        }
        for (; i < dg; ++i) {
            float4 ax = ap[i];
            float cv = isMsg ? ax.y : __cosf(fmaf(ax.x, twj, tbj));
            den0 += ax.z; den1 += ax.w;
            acc0 = fmaf(ax.z, cv, acc0);
            acc1 = fmaf(ax.w, cv, acc1);
        }
        if (act) {
            __half r0 = __float2half((dg > 0) ? acc0 / den0 : 0.f);
            __half r1 = __float2half((dg > 0) ? acc1 / den1 : 0.f);
            CWh[(size_t)n * CWS2 + j] = r0;               // head0 block [0,101)
            CWh[(size_t)n * CWS2 + EDGED + j] = r1;       // head1 block [101,202)
        }
    }
}

// ---------------- K3: MFMA CW GEMM: zbuf += CW[N x 202] * We2 ----------------
// A operand is fp16 exactly (CW stored half) -> single MFMA per tile.
__global__ __launch_bounds__(256) void k_gemmCW(
    const __half* __restrict__ CWh,
    const __half* __restrict__ WT2h,
    int N, float* __restrict__ zbuf)
{
    __shared__ __half ash[64][K2L];
    int tid = threadIdx.x;
    int m0 = blockIdx.x * 64;

    for (int idx = tid; idx < 64 * K2P; idx += 256) {
        int row = idx / K2P, k = idx - (idx / K2P) * K2P;
        int node = m0 + row;
        ash[row][k] = (k < 2 * EDGED && node < N) ? CWh[(size_t)node * CWS2 + k]
                                                  : __half(0.f);
    }
    __syncthreads();

    int wave = tid >> 6, lane = tid & 63;
    int arow = wave * 16 + (lane & 15);
    int kgrp = (lane >> 4) * 8;
    f32x4 acc[7];
#pragma unroll
    for (int c = 0; c < 7; ++c) acc[c] = f32x4{0.f, 0.f, 0.f, 0.f};

#pragma unroll
    for (int kk = 0; kk < K2P; kk += 32) {
        f16x8 ah = *(const f16x8*)&ash[arow][kk + kgrp];
#pragma unroll
        for (int c = 0; c < 7; ++c) {
            int col = c * 16 + (lane & 15);
            f16x8 bh = *(const f16x8*)&WT2h[col * K2P + kk + kgrp];
            acc[c] = __builtin_amdgcn_mfma_f32_16x16x32_f16(ah, bh, acc[c], 0, 0, 0);
        }
    }

#pragma unroll
    for (int c = 0; c < 7; ++c) {
        int col = c * 16 + (lane & 15);
        if (col >= TDIM) continue;
#pragma unroll
        for (int r = 0; r < 4; ++r) {
            int node = m0 + wave * 16 + (lane >> 4) * 4 + r;
            if (node >= N) continue;
            size_t o = (size_t)node * TDIM + col;
            zbuf[o] += acc[c][r];
        }
    }
}

// ---------------- K4: link predictor ----------------
#define LPB 64
__global__ __launch_bounds__(256) void k_link(
    const float* __restrict__ zout,
    const float* __restrict__ Wsr, const float* __restrict__ bsr,
    const float* __restrict__ Wds, const float* __restrict__ bds,
    const float* __restrict__ Wf, const float* __restrict__ bf,
    const int* __restrict__ assoc, const int* __restrict__ src,
    const int* __restrict__ dst, int B, float* __restrict__ outp)
{
    __shared__ float zs[LPB][EDGED];
    __shared__ float zd[LPB][EDGED];
    __shared__ int rowS[LPB], rowD[LPB];
    int tid = threadIdx.x;
    int l0 = blockIdx.x * LPB;
    if (tid < LPB) {
        int li = l0 + tid;
        rowS[tid] = (li < B) ? assoc[src[li]] : 0;
        rowD[tid] = (li < B) ? assoc[dst[li]] : 0;
    }
    __syncthreads();
    for (int i = tid; i < LPB * TDIM; i += 256) {
        int l = i / TDIM, d2 = i - l * TDIM;
        zs[l][d2] = zout[(size_t)rowS[l] * TDIM + d2];
        zd[l][d2] = zout[(size_t)rowD[l] * TDIM + d2];
    }
    __syncthreads();
    int l = tid >> 2, qt = tid & 3;
    float part = 0.f;
    for (int oo = 0; oo < 25; ++oo) {
        int out = qt * 25 + oo;
        const float4* ws4 = (const float4*)(Wsr + out * TDIM);
        const float4* wd4 = (const float4*)(Wds + out * TDIM);
        float accS = 0.f, accD = 0.f;
#pragma unroll
        for (int j = 0; j < 25; ++j) {
            float4 a = ws4[j];
            float4 b = wd4[j];
            accS = fmaf(a.x, zs[l][4*j+0], accS); accS = fmaf(a.y, zs[l][4*j+1], accS);
            accS = fmaf(a.z, zs[l][4*j+2], accS); accS = fmaf(a.w, zs[l][4*j+3], accS);
            accD = fmaf(b.x, zd[l][4*j+0], accD); accD = fmaf(b.y, zd[l][4*j+1], accD);
            accD = fmaf(b.z, zd[l][4*j+2], accD); accD = fmaf(b.w, zd[l][4*j+3], accD);
        }
        float h = accS + accD + bsr[out] + bds[out];
        h = fmaxf(h, 0.f);
        part = fmaf(Wf[out], h, part);
    }
    part += __shfl_xor(part, 1);
    part += __shfl_xor(part, 2);
    int li = l0 + l;
    if (qt == 0 && li < B) outp[li] = part + bf[0];
}

extern "C" void kernel_launch(void* const* d_in, const int* in_sizes, int n_in,
                              void* d_out, int out_size, void* d_ws, size_t ws_size,
                              hipStream_t stream)
{
    const float* z   = (const float*)d_in[0];
    const float* lu  = (const float*)d_in[1];
    const float* tt  = (const float*)d_in[2];
    const float* msg = (const float*)d_in[3];
    const float* tw  = (const float*)d_in[4];
    const float* tb  = (const float*)d_in[5];
    const float* Wq  = (const float*)d_in[6];  const float* bq  = (const float*)d_in[7];
    const float* Wk  = (const float*)d_in[8];  const float* bk  = (const float*)d_in[9];
    const float* Wv  = (const float*)d_in[10]; const float* bv  = (const float*)d_in[11];
    const float* We  = (const float*)d_in[12];
    const float* Wsk = (const float*)d_in[13]; const float* bsk = (const float*)d_in[14];
    const float* Wsr = (const float*)d_in[15]; const float* bsr = (const float*)d_in[16];
    const float* Wds = (const float*)d_in[17]; const float* bds = (const float*)d_in[18];
    const float* Wf  = (const float*)d_in[19]; const float* bf  = (const float*)d_in[20];
    const int* n_id  = (const int*)d_in[21];
    const int* srcI  = (const int*)d_in[22];
    const int* dstI  = (const int*)d_in[23];
    const int* ei    = (const int*)d_in[24];

    int N = in_sizes[0] / TDIM;   // 100000
    int E = in_sizes[2];          // 500000
    int B = in_sizes[22];         // 20000
    const size_t NUM_NODES = 1000000;
    int nblk = (N + SCB - 1) / SCB;

    char* w = (char*)d_ws;
    int*    assoc = (int*)w;    w += NUM_NODES * sizeof(int);          // 4.0 MB
    float2* auxrm = (float2*)w; w += (size_t)E * 8;                    // 4.0 MB
    float4* aux_s = (float4*)w; w += (size_t)E * 16;                   // 8.0 MB
    int*    esrcs = (int*)w;    w += (size_t)E * 4;                    // 2.0 MB
    int*    edst  = (int*)w;    w += (size_t)E * 4;                    // 2.0 MB
    __half* vh    = (__half*)w; w += (size_t)N * TDIM * 2;             // 20 MB
    float*  zbuf  = (float*)w;  w += (size_t)N * TDIM * 4;             // 40 MB
    // UNION: q/k/qW (GEMM+logit phase) aliased with CWh (gather+gemmCW phase)
    char*   uni   = w;
    __half* qh    = (__half*)uni;
    __half* kh    = (__half*)(uni + (size_t)N * TDIM * 2);
    __half* qW0h  = (__half*)(uni + (size_t)N * TDIM * 4);
    __half* qW1h  = (__half*)(uni + (size_t)N * TDIM * 4 + (size_t)N * EDGEP * 2);
    __half* CWh   = (__half*)uni;                                      // N*208*2 = 41.6 MB
    w += (size_t)N * TDIM * 4 + (size_t)N * EDGEP * 4;                 // 81.6 MB union
    __half* WTh   = (__half*)w; w += (size_t)NCOLP * KPAD * 2;         // 160 KB
    __half* WTl   = (__half*)w; w += (size_t)NCOLP * KPAD * 2;         // 160 KB (unused, layout keep)
    __half* WT2h  = (__half*)w; w += (size_t)NCOL2 * K2P * 2;          // 50 KB
    float*  biasA = (float*)w;  w += NCOLP * 4;
    int*    deg   = (int*)w;    w += (size_t)N * sizeof(int);
    int*    off   = (int*)w;    w += (size_t)N * sizeof(int);
    int*    curs  = (int*)w;    w += (size_t)N * sizeof(int);
    int*    bsum  = (int*)w;    w += 512 * sizeof(int);
    int*    bbase = (int*)w;    w += 512 * sizeof(int);
    // total ~163 MB

    hipLaunchKernelGGL(k_prep, dim3((N + 255) / 256), dim3(256), 0, stream,
                       n_id, N, assoc, deg);
    hipLaunchKernelGGL(k_precomp2,
                       dim3((NCOLP * KPAD + NCOL2 * K2P + NCOLP + 255) / 256), dim3(256), 0, stream,
                       Wq, bq, Wk, bk, Wv, bv, Wsk, bsk, We, WTh, WTl, WT2h, biasA);
    hipLaunchKernelGGL(k_count, dim3((E + 255) / 256), dim3(256), 0, stream, ei, E, deg);
    hipLaunchKernelGGL(k_scan1, dim3(nblk), dim3(SCB), 0, stream, deg, N, bsum);
    hipLaunchKernelGGL(k_scan2, dim3(1), dim3(512), 0, stream, bsum, nblk, bbase);
    hipLaunchKernelGGL(k_scan3, dim3(nblk), dim3(SCB), 0, stream, deg, N, bbase, off, curs);
    hipLaunchKernelGGL(k_fill2, dim3((E + 255) / 256), dim3(256), 0, stream,
                       ei, lu, tt, msg, E, curs, esrcs, edst, auxrm);
    hipLaunchKernelGGL(k_gemm, dim3((N + 63) / 64, 8), dim3(256), 0, stream,
                       z, WTh, biasA, qh, kh, vh, zbuf, qW0h, qW1h, N);
    hipLaunchKernelGGL(k_logit2, dim3((E + 255) / 256), dim3(256), 0, stream,
                       auxrm, esrcs, edst, tw, tb, qh, kh, qW0h, qW1h, E, aux_s);
    hipLaunchKernelGGL(k_gather4, dim3(N), dim3(256), 0, stream,
                       tw, tb, vh, esrcs, aux_s, off, deg, N, zbuf, CWh);
    hipLaunchKernelGGL(k_gemmCW, dim3((N + 63) / 64), dim3(256), 0, stream,
                       CWh, WT2h, N, zbuf);
    hipLaunchKernelGGL(k_link, dim3((B + LPB - 1) / LPB), dim3(256), 0, stream,
                       zbuf, Wsr, bsr, Wds, bds, Wf, bf, assoc, srcI, dstI, B,
                       (float*)d_out);
}